// Round 3
// baseline (1506.786 us; speedup 1.0000x reference)
//
#include <hip/hip_runtime.h>
#include <math.h>

#define BB 4
#define SSEQ 2048
#define DDIM 512
#define NSTATE 16
#define KCONV 4
#define NOPS_ 4
#define GAMMA_ 0.01f
#define CONDT_ 100.0f
#define SCALE_ 1.0f

static const size_t BSD = (size_t)BB * SSEQ * DDIM;    // 4194304
static const size_t BSN = (size_t)BB * SSEQ * NSTATE;  // 131072

// ---------------- complex GEMM:  C[M,512] = A[M,512] @ W[512,512]  ----------------
// 64x64 tile, 256 threads, 4x4 per thread. Optional Lindblad column scale epilogue.
template <bool LIND>
__global__ __launch_bounds__(256) void cgemm_kernel(
    const float* __restrict__ Ar, const float* __restrict__ Ai,
    const float* __restrict__ Wr, const float* __restrict__ Wi,
    const float* __restrict__ Lr, const float* __restrict__ Li,
    float* __restrict__ Cr, float* __restrict__ Ci)
{
    __shared__ float As_r[16][68], As_i[16][68], Bs_r[16][68], Bs_i[16][68];
    const int tid = threadIdx.x;
    const int tx = tid & 15, ty = tid >> 4;
    const int row0 = blockIdx.y * 64;
    const int col0 = blockIdx.x * 64;
    float accr[4][4] = {{0.f}}, acci[4][4] = {{0.f}};
    for (int k0 = 0; k0 < DDIM; k0 += 16) {
        {
            const int r = tid >> 2;
            const int k4 = (tid & 3) << 2;
            const float4 ar = *reinterpret_cast<const float4*>(Ar + (size_t)(row0 + r) * DDIM + k0 + k4);
            const float4 ai = *reinterpret_cast<const float4*>(Ai + (size_t)(row0 + r) * DDIM + k0 + k4);
            As_r[k4 + 0][r] = ar.x; As_r[k4 + 1][r] = ar.y; As_r[k4 + 2][r] = ar.z; As_r[k4 + 3][r] = ar.w;
            As_i[k4 + 0][r] = ai.x; As_i[k4 + 1][r] = ai.y; As_i[k4 + 2][r] = ai.z; As_i[k4 + 3][r] = ai.w;
            const int kk = tid >> 4;
            const int c4 = (tid & 15) << 2;
            const float4 br = *reinterpret_cast<const float4*>(Wr + (size_t)(k0 + kk) * DDIM + col0 + c4);
            const float4 bi = *reinterpret_cast<const float4*>(Wi + (size_t)(k0 + kk) * DDIM + col0 + c4);
            *reinterpret_cast<float4*>(&Bs_r[kk][c4]) = br;
            *reinterpret_cast<float4*>(&Bs_i[kk][c4]) = bi;
        }
        __syncthreads();
        #pragma unroll
        for (int k = 0; k < 16; ++k) {
            float ar[4], ai[4], br[4], bi[4];
            #pragma unroll
            for (int i = 0; i < 4; ++i) { ar[i] = As_r[k][ty * 4 + i]; ai[i] = As_i[k][ty * 4 + i]; }
            #pragma unroll
            for (int j = 0; j < 4; ++j) { br[j] = Bs_r[k][tx * 4 + j]; bi[j] = Bs_i[k][tx * 4 + j]; }
            #pragma unroll
            for (int i = 0; i < 4; ++i)
                #pragma unroll
                for (int j = 0; j < 4; ++j) {
                    accr[i][j] += ar[i] * br[j] - ai[i] * bi[j];
                    acci[i][j] += ar[i] * bi[j] + ai[i] * br[j];
                }
        }
        __syncthreads();
    }
    float lind[4] = {1.f, 1.f, 1.f, 1.f};
    if (LIND) {
        #pragma unroll
        for (int j = 0; j < 4; ++j) {
            const int col = col0 + tx * 4 + j;
            float s = 0.f;
            #pragma unroll
            for (int k = 0; k < NOPS_; ++k) {
                const float lr = Lr[k * DDIM + col], li = Li[k * DDIM + col];
                s += lr * lr + li * li;
            }
            lind[j] = 1.0f - GAMMA_ * s;
        }
    }
    #pragma unroll
    for (int i = 0; i < 4; ++i) {
        const size_t row = (size_t)(row0 + ty * 4 + i);
        float4 vr, vi;
        vr.x = accr[i][0] * lind[0]; vr.y = accr[i][1] * lind[1];
        vr.z = accr[i][2] * lind[2]; vr.w = accr[i][3] * lind[3];
        vi.x = acci[i][0] * lind[0]; vi.y = acci[i][1] * lind[1];
        vi.z = acci[i][2] * lind[2]; vi.w = acci[i][3] * lind[3];
        *reinterpret_cast<float4*>(Cr + row * DDIM + col0 + tx * 4) = vr;
        *reinterpret_cast<float4*>(Ci + row * DDIM + col0 + tx * 4) = vi;
    }
}

// ---------------- real GEMM for dt: softplus(A@W + b) ----------------
__global__ __launch_bounds__(256) void rgemm_dt_kernel(
    const float* __restrict__ A, const float* __restrict__ W,
    const float* __restrict__ bias, float* __restrict__ Out)
{
    __shared__ float As[16][68], Bs[16][68];
    const int tid = threadIdx.x;
    const int tx = tid & 15, ty = tid >> 4;
    const int row0 = blockIdx.y * 64;
    const int col0 = blockIdx.x * 64;
    float acc[4][4] = {{0.f}};
    for (int k0 = 0; k0 < DDIM; k0 += 16) {
        {
            const int r = tid >> 2;
            const int k4 = (tid & 3) << 2;
            const float4 av = *reinterpret_cast<const float4*>(A + (size_t)(row0 + r) * DDIM + k0 + k4);
            As[k4 + 0][r] = av.x; As[k4 + 1][r] = av.y; As[k4 + 2][r] = av.z; As[k4 + 3][r] = av.w;
            const int kk = tid >> 4;
            const int c4 = (tid & 15) << 2;
            const float4 bv = *reinterpret_cast<const float4*>(W + (size_t)(k0 + kk) * DDIM + col0 + c4);
            *reinterpret_cast<float4*>(&Bs[kk][c4]) = bv;
        }
        __syncthreads();
        #pragma unroll
        for (int k = 0; k < 16; ++k) {
            float a[4], b[4];
            #pragma unroll
            for (int i = 0; i < 4; ++i) a[i] = As[k][ty * 4 + i];
            #pragma unroll
            for (int j = 0; j < 4; ++j) b[j] = Bs[k][tx * 4 + j];
            #pragma unroll
            for (int i = 0; i < 4; ++i)
                #pragma unroll
                for (int j = 0; j < 4; ++j) acc[i][j] += a[i] * b[j];
        }
        __syncthreads();
    }
    #pragma unroll
    for (int i = 0; i < 4; ++i) {
        const size_t row = (size_t)(row0 + ty * 4 + i);
        float4 v;
        float* pv = &v.x;
        #pragma unroll
        for (int j = 0; j < 4; ++j) {
            const int col = col0 + tx * 4 + j;
            float z = acc[i][j] + bias[col];
            pv[j] = (z > 0.f) ? (z + log1pf(expf(-z))) : log1pf(expf(z));
        }
        *reinterpret_cast<float4*>(Out + row * DDIM + col0 + tx * 4) = v;
    }
}

// ---------------- causal depthwise conv + modSiLU gate ----------------
__global__ __launch_bounds__(256) void conv_gate_kernel(
    const float* __restrict__ ur, const float* __restrict__ ui,
    const float* __restrict__ w, float* __restrict__ gr, float* __restrict__ gi)
{
    const size_t idx = (size_t)blockIdx.x * 256 + threadIdx.x;  // < BSD
    const int d = (int)(idx % DDIM);
    const int s = (int)((idx / DDIM) % SSEQ);
    float ar = 0.f, ai = 0.f;
    #pragma unroll
    for (int k = 0; k < KCONV; ++k) {
        const int soff = s + k - (KCONV - 1);
        if (soff >= 0) {
            const size_t j = idx + (size_t)((long)(k - (KCONV - 1)) * DDIM);
            const float wk = w[k * DDIM + d];
            ar += wk * ur[j];
            ai += wk * ui[j];
        }
    }
    const float mag = sqrtf(ar * ar + ai * ai);
    const float sig = 1.0f / (1.0f + expf(-mag));
    gr[idx] = ar * sig;
    gi[idx] = ai * sig;
}

// ---------------- skinny B/C projections: [8192,512] @ [512,16] ----------------
__global__ __launch_bounds__(256) void bc_kernel(
    const float* __restrict__ xr, const float* __restrict__ WB,
    const float* __restrict__ WC, float* __restrict__ Bm, float* __restrict__ Cm)
{
    const int gid = blockIdx.x * 256 + threadIdx.x;  // < 131072
    const int row = gid >> 4, n = gid & 15;
    const float* xrow = xr + (size_t)row * DDIM;
    float ab = 0.f, ac = 0.f;
    for (int k = 0; k < DDIM; ++k) {
        const float xv = xrow[k];
        ab += xv * WB[k * NSTATE + n];
        ac += xv * WC[k * NSTATE + n];
    }
    Bm[gid] = ab;
    Cm[gid] = ac;
}

// ---------------- selective scan (sequential over S, 16 lanes per channel) ----------------
__global__ __launch_bounds__(256) void scan_kernel(
    const float* __restrict__ dt, const float* __restrict__ gr, const float* __restrict__ gi,
    const float* __restrict__ Bm, const float* __restrict__ Cm,
    const float* __restrict__ A_log, const float* __restrict__ D_skip,
    float* __restrict__ yr, float* __restrict__ yi)
{
    __shared__ float dt_s[64][16], gr_s[64][16], gi_s[64][16];
    __shared__ float bm_s[64][16], cm_s[64][16];
    __shared__ float yr_s[64][16], yi_s[64][16];
    const int b = blockIdx.x >> 5;          // 0..3
    const int d0 = (blockIdx.x & 31) * 16;  // 0..496
    const int tid = threadIdx.x;
    const int lane = tid & 63, wv = tid >> 6;
    const int c = wv * 4 + (lane >> 4);     // channel within block, 0..15
    const int n = lane & 15;                // state index
    const int d = d0 + c;
    const float A_dn = -expf(A_log[d * NSTATE + n]);
    const float dsk = D_skip[d];
    float hr = 0.f, hi = 0.f;
    for (int s0 = 0; s0 < SSEQ; s0 += 64) {
        #pragma unroll
        for (int it = 0; it < 4; ++it) {
            const int idx = it * 256 + tid;  // 0..1023
            const int i = idx >> 4, j = idx & 15;
            const size_t g = (size_t)b * SSEQ * DDIM + (size_t)(s0 + i) * DDIM + d0 + j;
            dt_s[i][j] = dt[g];
            gr_s[i][j] = gr[g];
            gi_s[i][j] = gi[g];
            const size_t gb = (size_t)b * SSEQ * NSTATE + (size_t)(s0 + i) * NSTATE + j;
            bm_s[i][j] = Bm[gb];
            cm_s[i][j] = Cm[gb];
        }
        __syncthreads();
        for (int i = 0; i < 64; ++i) {
            const float dtv = dt_s[i][c];
            const float uvr = gr_s[i][c], uvi = gi_s[i][c];
            const float bm = bm_s[i][n], cm = cm_s[i][n];
            const float decay = expf(dtv * A_dn);
            hr = decay * hr + dtv * uvr * bm;
            hi = decay * hi + dtv * uvi * bm;
            float pr = hr * cm, pi = hi * cm;
            #pragma unroll
            for (int off = 8; off; off >>= 1) {
                pr += __shfl_xor(pr, off);
                pi += __shfl_xor(pi, off);
            }
            if (n == 0) {
                yr_s[i][c] = pr + dsk * uvr;
                yi_s[i][c] = pi + dsk * uvi;
            }
        }
        __syncthreads();
        #pragma unroll
        for (int it = 0; it < 4; ++it) {
            const int idx = it * 256 + tid;
            const int i = idx >> 4, j = idx & 15;
            const size_t g = (size_t)b * SSEQ * DDIM + (size_t)(s0 + i) * DDIM + d0 + j;
            yr[g] = yr_s[i][j];
            yi[g] = yi_s[i][j];
        }
        __syncthreads();
    }
}

// ---------------- diag[b,d] = mean_s |branch|^2 ----------------
__global__ __launch_bounds__(256) void diag_kernel(
    const float* __restrict__ br, const float* __restrict__ bi, float* __restrict__ diag)
{
    const int b = blockIdx.x >> 4;
    const int s0 = (blockIdx.x & 15) * 128;
    const int t = threadIdx.x;
    float a0 = 0.f, a1 = 0.f;
    for (int i = 0; i < 128; ++i) {
        const size_t g = (size_t)b * SSEQ * DDIM + (size_t)(s0 + i) * DDIM;
        const float r0 = br[g + t], i0 = bi[g + t];
        const float r1 = br[g + t + 256], i1 = bi[g + t + 256];
        a0 += r0 * r0 + i0 * i0;
        a1 += r1 * r1 + i1 * i1;
    }
    const float inv = 1.0f / (float)SSEQ;
    atomicAdd(&diag[b * DDIM + t], a0 * inv);
    atomicAdd(&diag[b * DDIM + t + 256], a1 * inv);
}

// ---------------- escape flags + sinkhorn coef + rotation table ----------------
__global__ __launch_bounds__(256) void escape_kernel(
    const float* __restrict__ diag, const float* __restrict__ phi,
    const float* __restrict__ logit, const float* __restrict__ logit_im,
    float* __restrict__ misc, float* __restrict__ rot_r, float* __restrict__ rot_i)
{
    const int tid = threadIdx.x;
    rot_r[tid] = cosf(phi[tid]);
    rot_i[tid] = sinf(phi[tid]);
    rot_r[tid + 256] = cosf(phi[tid + 256]);
    rot_i[tid + 256] = sinf(phi[tid + 256]);
    const int b = tid >> 6, lane = tid & 63;
    float mx = -1e30f, mn = 1e30f;
    for (int j = lane; j < DDIM; j += 64) {
        const float v = diag[b * DDIM + j];
        mx = fmaxf(mx, v);
        mn = fminf(mn, v);
    }
    #pragma unroll
    for (int off = 32; off; off >>= 1) {
        mx = fmaxf(mx, __shfl_xor(mx, off));
        mn = fminf(mn, __shfl_xor(mn, off));
    }
    if (lane == 0) {
        const float cond = mx / (mn + 1e-8f);
        misc[b] = (cond > CONDT_) ? 1.0f : 0.0f;
    }
    if (tid == 0) {
        float M = expf(logit[0] / 0.05f);
        for (int it = 0; it < 10; ++it) { M = M / M; M = M / M; }
        const float im = logit_im[0];
        misc[4] = M * cosf(im);
        misc[5] = M * sinf(im);
    }
}

// ---------------- final: rotate-if-escaped, coef multiply, residual add ----------------
__global__ __launch_bounds__(256) void final_kernel(
    const float* __restrict__ xr, const float* __restrict__ xi,
    const float* __restrict__ br, const float* __restrict__ bi,
    const float* __restrict__ misc, const float* __restrict__ rot_r,
    const float* __restrict__ rot_i, float* __restrict__ out)
{
    const size_t idx = (size_t)blockIdx.x * 256 + threadIdx.x;  // < BSD
    const int d = (int)(idx % DDIM);
    const int b = (int)(idx / ((size_t)SSEQ * DDIM));
    float r = br[idx], im = bi[idx];
    if (misc[b] != 0.0f) {
        const float rr = rot_r[d], ri = rot_i[d];
        const float nr = r * rr - im * ri;
        const float ni = r * ri + im * rr;
        r = nr;
        im = ni;
    }
    r *= SCALE_;
    im *= SCALE_;
    const float cr = misc[4], ci = misc[5];
    const float outr = r * cr - im * ci;
    const float outi = im * cr + r * ci;
    out[idx] = xr[idx] + outr;
    out[BSD + idx] = xi[idx] + outi;
}

extern "C" void kernel_launch(void* const* d_in, const int* in_sizes, int n_in,
                              void* d_out, int out_size, void* d_ws, size_t ws_size,
                              hipStream_t stream)
{
    (void)in_sizes; (void)n_in; (void)out_size; (void)ws_size;
    const float* x_r    = (const float*)d_in[0];
    const float* x_i    = (const float*)d_in[1];
    const float* Win_r  = (const float*)d_in[2];
    const float* Win_i  = (const float*)d_in[3];
    const float* convw  = (const float*)d_in[4];
    const float* W_dt   = (const float*)d_in[5];
    const float* b_dt   = (const float*)d_in[6];
    const float* A_log  = (const float*)d_in[7];
    const float* W_B    = (const float*)d_in[8];
    const float* W_C    = (const float*)d_in[9];
    const float* D_skip = (const float*)d_in[10];
    const float* Wout_r = (const float*)d_in[11];
    const float* Wout_i = (const float*)d_in[12];
    const float* L_r    = (const float*)d_in[13];
    const float* L_i    = (const float*)d_in[14];
    const float* phi    = (const float*)d_in[15];
    const float* hres   = (const float*)d_in[16];
    const float* hresi  = (const float*)d_in[17];
    float* out = (float*)d_out;

    float* f    = (float*)d_ws;
    float* u_r  = f;
    float* u_i  = f + BSD;
    float* g_r  = f + 2 * BSD;
    float* g_i  = f + 3 * BSD;
    float* dt   = f + 4 * BSD;
    float* y_r  = f + 5 * BSD;
    float* y_i  = f + 6 * BSD;
    float* Bm   = f + 7 * BSD;
    float* Cm   = Bm + BSN;
    float* diag = Cm + BSN;
    float* misc = diag + (size_t)BB * DDIM;
    float* rot_r = misc + 8;
    float* rot_i = rot_r + DDIM;
    float* br_r = u_r;  // reuse (u dead after conv)
    float* br_i = u_i;

    // 1. complex in-projection
    cgemm_kernel<false><<<dim3(8, 128), 256, 0, stream>>>(
        x_r, x_i, Win_r, Win_i, nullptr, nullptr, u_r, u_i);
    // 2. causal conv + modSiLU gate
    conv_gate_kernel<<<(int)(BSD / 256), 256, 0, stream>>>(u_r, u_i, convw, g_r, g_i);
    // 3. dt projection (+bias, softplus)
    rgemm_dt_kernel<<<dim3(8, 128), 256, 0, stream>>>(g_r, W_dt, b_dt, dt);
    // 4. B/C projections
    bc_kernel<<<512, 256, 0, stream>>>(g_r, W_B, W_C, Bm, Cm);
    // 5. selective scan (+ D_skip)
    scan_kernel<<<128, 256, 0, stream>>>(dt, g_r, g_i, Bm, Cm, A_log, D_skip, y_r, y_i);
    // 6. complex out-projection (+ Lindblad scale)
    cgemm_kernel<true><<<dim3(8, 128), 256, 0, stream>>>(
        y_r, y_i, Wout_r, Wout_i, L_r, L_i, br_r, br_i);
    // 7. diag power + escape + coef
    hipMemsetAsync(diag, 0, (size_t)BB * DDIM * sizeof(float), stream);
    diag_kernel<<<64, 256, 0, stream>>>(br_r, br_i, diag);
    escape_kernel<<<1, 256, 0, stream>>>(diag, phi, hres, hresi, misc, rot_r, rot_i);
    // 8. final combine
    final_kernel<<<(int)(BSD / 256), 256, 0, stream>>>(
        x_r, x_i, br_r, br_i, misc, rot_r, rot_i, out);
}

// Round 4
// 1043.763 us; speedup vs baseline: 1.4436x; 1.4436x over previous
//
#include <hip/hip_runtime.h>
#include <math.h>

#define BB 4
#define SSEQ 2048
#define DDIM 512
#define NSTATE 16
#define KCONV 4
#define NOPS_ 4
#define GAMMA_ 0.01f
#define CONDT_ 100.0f
#define SCALE_ 1.0f
#define NC 64   // chunks over S
#define LC 32   // steps per chunk

static const size_t BSD = (size_t)BB * SSEQ * DDIM;    // 4194304
static const size_t BSN = (size_t)BB * SSEQ * NSTATE;  // 131072
static const size_t MIDSZ = (size_t)BB * NC * DDIM * NSTATE;  // 2097152

// ---------------- complex GEMM:  C[M,512] = A[M,512] @ W[512,512]  ----------------
template <bool LIND>
__global__ __launch_bounds__(256) void cgemm_kernel(
    const float* __restrict__ Ar, const float* __restrict__ Ai,
    const float* __restrict__ Wr, const float* __restrict__ Wi,
    const float* __restrict__ Lr, const float* __restrict__ Li,
    float* __restrict__ Cr, float* __restrict__ Ci)
{
    __shared__ float As_r[16][68], As_i[16][68], Bs_r[16][68], Bs_i[16][68];
    const int tid = threadIdx.x;
    const int tx = tid & 15, ty = tid >> 4;
    const int row0 = blockIdx.y * 64;
    const int col0 = blockIdx.x * 64;
    float accr[4][4] = {{0.f}}, acci[4][4] = {{0.f}};
    for (int k0 = 0; k0 < DDIM; k0 += 16) {
        {
            const int r = tid >> 2;
            const int k4 = (tid & 3) << 2;
            const float4 ar = *reinterpret_cast<const float4*>(Ar + (size_t)(row0 + r) * DDIM + k0 + k4);
            const float4 ai = *reinterpret_cast<const float4*>(Ai + (size_t)(row0 + r) * DDIM + k0 + k4);
            As_r[k4 + 0][r] = ar.x; As_r[k4 + 1][r] = ar.y; As_r[k4 + 2][r] = ar.z; As_r[k4 + 3][r] = ar.w;
            As_i[k4 + 0][r] = ai.x; As_i[k4 + 1][r] = ai.y; As_i[k4 + 2][r] = ai.z; As_i[k4 + 3][r] = ai.w;
            const int kk = tid >> 4;
            const int c4 = (tid & 15) << 2;
            const float4 br = *reinterpret_cast<const float4*>(Wr + (size_t)(k0 + kk) * DDIM + col0 + c4);
            const float4 bi = *reinterpret_cast<const float4*>(Wi + (size_t)(k0 + kk) * DDIM + col0 + c4);
            *reinterpret_cast<float4*>(&Bs_r[kk][c4]) = br;
            *reinterpret_cast<float4*>(&Bs_i[kk][c4]) = bi;
        }
        __syncthreads();
        #pragma unroll
        for (int k = 0; k < 16; ++k) {
            float ar[4], ai[4], br[4], bi[4];
            #pragma unroll
            for (int i = 0; i < 4; ++i) { ar[i] = As_r[k][ty * 4 + i]; ai[i] = As_i[k][ty * 4 + i]; }
            #pragma unroll
            for (int j = 0; j < 4; ++j) { br[j] = Bs_r[k][tx * 4 + j]; bi[j] = Bs_i[k][tx * 4 + j]; }
            #pragma unroll
            for (int i = 0; i < 4; ++i)
                #pragma unroll
                for (int j = 0; j < 4; ++j) {
                    accr[i][j] += ar[i] * br[j] - ai[i] * bi[j];
                    acci[i][j] += ar[i] * bi[j] + ai[i] * br[j];
                }
        }
        __syncthreads();
    }
    float lind[4] = {1.f, 1.f, 1.f, 1.f};
    if (LIND) {
        #pragma unroll
        for (int j = 0; j < 4; ++j) {
            const int col = col0 + tx * 4 + j;
            float s = 0.f;
            #pragma unroll
            for (int k = 0; k < NOPS_; ++k) {
                const float lr = Lr[k * DDIM + col], li = Li[k * DDIM + col];
                s += lr * lr + li * li;
            }
            lind[j] = 1.0f - GAMMA_ * s;
        }
    }
    #pragma unroll
    for (int i = 0; i < 4; ++i) {
        const size_t row = (size_t)(row0 + ty * 4 + i);
        float4 vr, vi;
        vr.x = accr[i][0] * lind[0]; vr.y = accr[i][1] * lind[1];
        vr.z = accr[i][2] * lind[2]; vr.w = accr[i][3] * lind[3];
        vi.x = acci[i][0] * lind[0]; vi.y = acci[i][1] * lind[1];
        vi.z = acci[i][2] * lind[2]; vi.w = acci[i][3] * lind[3];
        *reinterpret_cast<float4*>(Cr + row * DDIM + col0 + tx * 4) = vr;
        *reinterpret_cast<float4*>(Ci + row * DDIM + col0 + tx * 4) = vi;
    }
}

// ---------------- real GEMM for dt: softplus(A@W + b) ----------------
__global__ __launch_bounds__(256) void rgemm_dt_kernel(
    const float* __restrict__ A, const float* __restrict__ W,
    const float* __restrict__ bias, float* __restrict__ Out)
{
    __shared__ float As[16][68], Bs[16][68];
    const int tid = threadIdx.x;
    const int tx = tid & 15, ty = tid >> 4;
    const int row0 = blockIdx.y * 64;
    const int col0 = blockIdx.x * 64;
    float acc[4][4] = {{0.f}};
    for (int k0 = 0; k0 < DDIM; k0 += 16) {
        {
            const int r = tid >> 2;
            const int k4 = (tid & 3) << 2;
            const float4 av = *reinterpret_cast<const float4*>(A + (size_t)(row0 + r) * DDIM + k0 + k4);
            As[k4 + 0][r] = av.x; As[k4 + 1][r] = av.y; As[k4 + 2][r] = av.z; As[k4 + 3][r] = av.w;
            const int kk = tid >> 4;
            const int c4 = (tid & 15) << 2;
            const float4 bv = *reinterpret_cast<const float4*>(W + (size_t)(k0 + kk) * DDIM + col0 + c4);
            *reinterpret_cast<float4*>(&Bs[kk][c4]) = bv;
        }
        __syncthreads();
        #pragma unroll
        for (int k = 0; k < 16; ++k) {
            float a[4], b[4];
            #pragma unroll
            for (int i = 0; i < 4; ++i) a[i] = As[k][ty * 4 + i];
            #pragma unroll
            for (int j = 0; j < 4; ++j) b[j] = Bs[k][tx * 4 + j];
            #pragma unroll
            for (int i = 0; i < 4; ++i)
                #pragma unroll
                for (int j = 0; j < 4; ++j) acc[i][j] += a[i] * b[j];
        }
        __syncthreads();
    }
    #pragma unroll
    for (int i = 0; i < 4; ++i) {
        const size_t row = (size_t)(row0 + ty * 4 + i);
        float4 v;
        float* pv = &v.x;
        #pragma unroll
        for (int j = 0; j < 4; ++j) {
            const int col = col0 + tx * 4 + j;
            float z = acc[i][j] + bias[col];
            pv[j] = (z > 0.f) ? (z + log1pf(expf(-z))) : log1pf(expf(z));
        }
        *reinterpret_cast<float4*>(Out + row * DDIM + col0 + tx * 4) = v;
    }
}

// ---------------- causal depthwise conv + modSiLU gate ----------------
__global__ __launch_bounds__(256) void conv_gate_kernel(
    const float* __restrict__ ur, const float* __restrict__ ui,
    const float* __restrict__ w, float* __restrict__ gr, float* __restrict__ gi)
{
    const size_t idx = (size_t)blockIdx.x * 256 + threadIdx.x;  // < BSD
    const int d = (int)(idx % DDIM);
    const int s = (int)((idx / DDIM) % SSEQ);
    float ar = 0.f, ai = 0.f;
    #pragma unroll
    for (int k = 0; k < KCONV; ++k) {
        const int soff = s + k - (KCONV - 1);
        if (soff >= 0) {
            const size_t j = idx + (size_t)((long)(k - (KCONV - 1)) * DDIM);
            const float wk = w[k * DDIM + d];
            ar += wk * ur[j];
            ai += wk * ui[j];
        }
    }
    const float mag = sqrtf(ar * ar + ai * ai);
    const float sig = 1.0f / (1.0f + expf(-mag));
    gr[idx] = ar * sig;
    gi[idx] = ai * sig;
}

// ---------------- skinny B/C projections: [8192,512] @ [512,16] ----------------
__global__ __launch_bounds__(256) void bc_kernel(
    const float* __restrict__ xr, const float* __restrict__ WB,
    const float* __restrict__ WC, float* __restrict__ Bm, float* __restrict__ Cm)
{
    const int gid = blockIdx.x * 256 + threadIdx.x;  // < 131072
    const int row = gid >> 4, n = gid & 15;
    const float* xrow = xr + (size_t)row * DDIM;
    float ab = 0.f, ac = 0.f;
    for (int k = 0; k < DDIM; ++k) {
        const float xv = xrow[k];
        ab += xv * WB[k * NSTATE + n];
        ac += xv * WC[k * NSTATE + n];
    }
    Bm[gid] = ab;
    Cm[gid] = ac;
}

// ---------------- chunked selective scan, phase 1: local scan from zero ----------------
// thread = (b, chunk, d); 16 states in registers. 512 blocks x 256.
__global__ __launch_bounds__(256) void scan_phase1(
    const float* __restrict__ dt, const float* __restrict__ gr, const float* __restrict__ gi,
    const float* __restrict__ Bm, const float* __restrict__ A_log,
    float* __restrict__ mid_hr, float* __restrict__ mid_hi, float* __restrict__ dtsum)
{
    __shared__ float bm_s[LC * NSTATE];
    const int blk = blockIdx.x;
    const int dblk = blk & 1;
    const int c = (blk >> 1) & (NC - 1);
    const int b = blk >> 7;
    const int tid = threadIdx.x;
    const int d = dblk * 256 + tid;
    const int s0 = c * LC;
    {
        const size_t base = ((size_t)b * SSEQ + s0) * NSTATE;
        bm_s[tid] = Bm[base + tid];
        bm_s[tid + 256] = Bm[base + tid + 256];
    }
    float A_dn[16], hr[16], hi[16];
    #pragma unroll
    for (int n = 0; n < 16; ++n) {
        A_dn[n] = -expf(A_log[d * NSTATE + n]);
        hr[n] = 0.f; hi[n] = 0.f;
    }
    float dts = 0.f;
    __syncthreads();
    const size_t gbase = (size_t)b * SSEQ * DDIM + (size_t)s0 * DDIM + d;
    for (int i = 0; i < LC; ++i) {
        const float dtv = dt[gbase + (size_t)i * DDIM];
        const float ur = gr[gbase + (size_t)i * DDIM];
        const float ui = gi[gbase + (size_t)i * DDIM];
        dts += dtv;
        const float xr = dtv * ur, xi = dtv * ui;
        #pragma unroll
        for (int n = 0; n < 16; ++n) {
            const float a = expf(dtv * A_dn[n]);
            const float bmv = bm_s[i * 16 + n];
            hr[n] = a * hr[n] + xr * bmv;
            hi[n] = a * hi[n] + xi * bmv;
        }
    }
    const size_t mbase = ((size_t)(b * NC + c) * DDIM + d) * NSTATE;
    #pragma unroll
    for (int n = 0; n < 16; ++n) { mid_hr[mbase + n] = hr[n]; mid_hi[mbase + n] = hi[n]; }
    dtsum[(size_t)(b * NC + c) * DDIM + d] = dts;
}

// ---------------- phase 2: combine chunk states (seq over NC, parallel over channels) ----
__global__ __launch_bounds__(256) void scan_phase2(
    const float* __restrict__ mid_hr, const float* __restrict__ mid_hi,
    const float* __restrict__ dtsum, const float* __restrict__ A_log,
    float* __restrict__ hinit_r, float* __restrict__ hinit_i)
{
    const int gid = blockIdx.x * 256 + threadIdx.x;  // < 32768
    const int n = gid & 15;
    const int d = (gid >> 4) & (DDIM - 1);
    const int b = gid >> 13;
    const float A_dn = -expf(A_log[d * NSTATE + n]);
    float hr = 0.f, hi = 0.f;
    for (int c = 0; c < NC; ++c) {
        const size_t cb = (size_t)(b * NC + c) * DDIM + d;
        hinit_r[cb * NSTATE + n] = hr;
        hinit_i[cb * NSTATE + n] = hi;
        const float P = expf(A_dn * dtsum[cb]);
        hr = mid_hr[cb * NSTATE + n] + P * hr;
        hi = mid_hi[cb * NSTATE + n] + P * hi;
    }
}

// ---------------- phase 3: recompute with true init, emit y (+D_skip) ----------------
__global__ __launch_bounds__(256) void scan_phase3(
    const float* __restrict__ dt, const float* __restrict__ gr, const float* __restrict__ gi,
    const float* __restrict__ Bm, const float* __restrict__ Cm,
    const float* __restrict__ A_log, const float* __restrict__ D_skip,
    const float* __restrict__ hinit_r, const float* __restrict__ hinit_i,
    float* __restrict__ yr, float* __restrict__ yi)
{
    __shared__ float bm_s[LC * NSTATE], cm_s[LC * NSTATE];
    const int blk = blockIdx.x;
    const int dblk = blk & 1;
    const int c = (blk >> 1) & (NC - 1);
    const int b = blk >> 7;
    const int tid = threadIdx.x;
    const int d = dblk * 256 + tid;
    const int s0 = c * LC;
    {
        const size_t base = ((size_t)b * SSEQ + s0) * NSTATE;
        bm_s[tid] = Bm[base + tid];
        bm_s[tid + 256] = Bm[base + tid + 256];
        cm_s[tid] = Cm[base + tid];
        cm_s[tid + 256] = Cm[base + tid + 256];
    }
    float A_dn[16], hr[16], hi[16];
    const size_t mbase = ((size_t)(b * NC + c) * DDIM + d) * NSTATE;
    #pragma unroll
    for (int n = 0; n < 16; ++n) {
        A_dn[n] = -expf(A_log[d * NSTATE + n]);
        hr[n] = hinit_r[mbase + n];
        hi[n] = hinit_i[mbase + n];
    }
    const float dsk = D_skip[d];
    __syncthreads();
    const size_t gbase = (size_t)b * SSEQ * DDIM + (size_t)s0 * DDIM + d;
    for (int i = 0; i < LC; ++i) {
        const float dtv = dt[gbase + (size_t)i * DDIM];
        const float ur = gr[gbase + (size_t)i * DDIM];
        const float ui = gi[gbase + (size_t)i * DDIM];
        const float xr = dtv * ur, xi = dtv * ui;
        float accr = dsk * ur, acci = dsk * ui;
        #pragma unroll
        for (int n = 0; n < 16; ++n) {
            const float a = expf(dtv * A_dn[n]);
            const float bmv = bm_s[i * 16 + n], cmv = cm_s[i * 16 + n];
            hr[n] = a * hr[n] + xr * bmv;
            hi[n] = a * hi[n] + xi * bmv;
            accr += hr[n] * cmv;
            acci += hi[n] * cmv;
        }
        yr[gbase + (size_t)i * DDIM] = accr;
        yi[gbase + (size_t)i * DDIM] = acci;
    }
}

// ---------------- diag[b,d] = mean_s |branch|^2 ----------------
__global__ __launch_bounds__(256) void diag_kernel(
    const float* __restrict__ br, const float* __restrict__ bi, float* __restrict__ diag)
{
    const int b = blockIdx.x >> 4;
    const int s0 = (blockIdx.x & 15) * 128;
    const int t = threadIdx.x;
    float a0 = 0.f, a1 = 0.f;
    for (int i = 0; i < 128; ++i) {
        const size_t g = (size_t)b * SSEQ * DDIM + (size_t)(s0 + i) * DDIM;
        const float r0 = br[g + t], i0 = bi[g + t];
        const float r1 = br[g + t + 256], i1 = bi[g + t + 256];
        a0 += r0 * r0 + i0 * i0;
        a1 += r1 * r1 + i1 * i1;
    }
    const float inv = 1.0f / (float)SSEQ;
    atomicAdd(&diag[b * DDIM + t], a0 * inv);
    atomicAdd(&diag[b * DDIM + t + 256], a1 * inv);
}

// ---------------- escape flags + sinkhorn coef + rotation table ----------------
__global__ __launch_bounds__(256) void escape_kernel(
    const float* __restrict__ diag, const float* __restrict__ phi,
    const float* __restrict__ logit, const float* __restrict__ logit_im,
    float* __restrict__ misc, float* __restrict__ rot_r, float* __restrict__ rot_i)
{
    const int tid = threadIdx.x;
    rot_r[tid] = cosf(phi[tid]);
    rot_i[tid] = sinf(phi[tid]);
    rot_r[tid + 256] = cosf(phi[tid + 256]);
    rot_i[tid + 256] = sinf(phi[tid + 256]);
    const int b = tid >> 6, lane = tid & 63;
    float mx = -1e30f, mn = 1e30f;
    for (int j = lane; j < DDIM; j += 64) {
        const float v = diag[b * DDIM + j];
        mx = fmaxf(mx, v);
        mn = fminf(mn, v);
    }
    #pragma unroll
    for (int off = 32; off; off >>= 1) {
        mx = fmaxf(mx, __shfl_xor(mx, off));
        mn = fminf(mn, __shfl_xor(mn, off));
    }
    if (lane == 0) {
        const float cond = mx / (mn + 1e-8f);
        misc[b] = (cond > CONDT_) ? 1.0f : 0.0f;
    }
    if (tid == 0) {
        float M = expf(logit[0] / 0.05f);
        for (int it = 0; it < 10; ++it) { M = M / M; M = M / M; }
        const float im = logit_im[0];
        misc[4] = M * cosf(im);
        misc[5] = M * sinf(im);
    }
}

// ---------------- final: rotate-if-escaped, coef multiply, residual add ----------------
__global__ __launch_bounds__(256) void final_kernel(
    const float* __restrict__ xr, const float* __restrict__ xi,
    const float* __restrict__ br, const float* __restrict__ bi,
    const float* __restrict__ misc, const float* __restrict__ rot_r,
    const float* __restrict__ rot_i, float* __restrict__ out)
{
    const size_t idx = (size_t)blockIdx.x * 256 + threadIdx.x;  // < BSD
    const int d = (int)(idx % DDIM);
    const int b = (int)(idx / ((size_t)SSEQ * DDIM));
    float r = br[idx], im = bi[idx];
    if (misc[b] != 0.0f) {
        const float rr = rot_r[d], ri = rot_i[d];
        const float nr = r * rr - im * ri;
        const float ni = r * ri + im * rr;
        r = nr;
        im = ni;
    }
    r *= SCALE_;
    im *= SCALE_;
    const float cr = misc[4], ci = misc[5];
    const float outr = r * cr - im * ci;
    const float outi = im * cr + r * ci;
    out[idx] = xr[idx] + outr;
    out[BSD + idx] = xi[idx] + outi;
}

extern "C" void kernel_launch(void* const* d_in, const int* in_sizes, int n_in,
                              void* d_out, int out_size, void* d_ws, size_t ws_size,
                              hipStream_t stream)
{
    (void)in_sizes; (void)n_in; (void)out_size; (void)ws_size;
    const float* x_r    = (const float*)d_in[0];
    const float* x_i    = (const float*)d_in[1];
    const float* Win_r  = (const float*)d_in[2];
    const float* Win_i  = (const float*)d_in[3];
    const float* convw  = (const float*)d_in[4];
    const float* W_dt   = (const float*)d_in[5];
    const float* b_dt   = (const float*)d_in[6];
    const float* A_log  = (const float*)d_in[7];
    const float* W_B    = (const float*)d_in[8];
    const float* W_C    = (const float*)d_in[9];
    const float* D_skip = (const float*)d_in[10];
    const float* Wout_r = (const float*)d_in[11];
    const float* Wout_i = (const float*)d_in[12];
    const float* L_r    = (const float*)d_in[13];
    const float* L_i    = (const float*)d_in[14];
    const float* phi    = (const float*)d_in[15];
    const float* hres   = (const float*)d_in[16];
    const float* hresi  = (const float*)d_in[17];
    float* out = (float*)d_out;

    float* f    = (float*)d_ws;
    float* u_r  = f;
    float* u_i  = f + BSD;
    float* g_r  = f + 2 * BSD;
    float* g_i  = f + 3 * BSD;
    float* dt   = f + 4 * BSD;
    float* y_r  = f + 5 * BSD;
    float* y_i  = f + 6 * BSD;
    float* Bm   = f + 7 * BSD;
    float* Cm   = Bm + BSN;
    float* dtsum = Cm + BSN;                       // BB*NC*DDIM = 131072
    float* diag = dtsum + (size_t)BB * NC * DDIM;
    float* misc = diag + (size_t)BB * DDIM;
    float* rot_r = misc + 8;
    float* rot_i = rot_r + DDIM;
    // scan scratch aliased into dead u buffers (u dead after conv_gate;
    // overwritten again only at cgemm<true> output time, after phase3)
    float* mid_hr  = u_r;            // MIDSZ
    float* mid_hi  = u_r + MIDSZ;    // MIDSZ (u_r holds exactly 2*MIDSZ)
    float* hinit_r = u_i;
    float* hinit_i = u_i + MIDSZ;
    float* br_r = u_r;  // branch output reuses u after scan scratch is dead
    float* br_i = u_i;

    // 1. complex in-projection
    cgemm_kernel<false><<<dim3(8, 128), 256, 0, stream>>>(
        x_r, x_i, Win_r, Win_i, nullptr, nullptr, u_r, u_i);
    // 2. causal conv + modSiLU gate
    conv_gate_kernel<<<(int)(BSD / 256), 256, 0, stream>>>(u_r, u_i, convw, g_r, g_i);
    // 3. dt projection (+bias, softplus)
    rgemm_dt_kernel<<<dim3(8, 128), 256, 0, stream>>>(g_r, W_dt, b_dt, dt);
    // 4. B/C projections
    bc_kernel<<<512, 256, 0, stream>>>(g_r, W_B, W_C, Bm, Cm);
    // 5. chunked selective scan (+ D_skip)
    scan_phase1<<<BB * NC * 2, 256, 0, stream>>>(dt, g_r, g_i, Bm, A_log, mid_hr, mid_hi, dtsum);
    scan_phase2<<<128, 256, 0, stream>>>(mid_hr, mid_hi, dtsum, A_log, hinit_r, hinit_i);
    scan_phase3<<<BB * NC * 2, 256, 0, stream>>>(dt, g_r, g_i, Bm, Cm, A_log, D_skip,
                                                 hinit_r, hinit_i, y_r, y_i);
    // 6. complex out-projection (+ Lindblad scale)
    cgemm_kernel<true><<<dim3(8, 128), 256, 0, stream>>>(
        y_r, y_i, Wout_r, Wout_i, L_r, L_i, br_r, br_i);
    // 7. diag power + escape + coef
    hipMemsetAsync(diag, 0, (size_t)BB * DDIM * sizeof(float), stream);
    diag_kernel<<<64, 256, 0, stream>>>(br_r, br_i, diag);
    escape_kernel<<<1, 256, 0, stream>>>(diag, phi, hres, hresi, misc, rot_r, rot_i);
    // 8. final combine
    final_kernel<<<(int)(BSD / 256), 256, 0, stream>>>(
        x_r, x_i, br_r, br_i, misc, rot_r, rot_i, out);
}

// Round 8
// 585.998 us; speedup vs baseline: 2.5713x; 1.7812x over previous
//
#include <hip/hip_runtime.h>
#include <math.h>

#define BB 4
#define SSEQ 2048
#define DDIM 512
#define NSTATE 16
#define KCONV 4
#define NOPS_ 4
#define GAMMA_ 0.01f
#define CONDT_ 100.0f
#define SCALE_ 1.0f
#define NC 64   // chunks over S
#define LC 32   // steps per chunk

static const size_t BSD = (size_t)BB * SSEQ * DDIM;    // 4194304
static const size_t BSN = (size_t)BB * SSEQ * NSTATE;  // 131072
static const size_t MIDSZ = (size_t)BB * NC * DDIM * NSTATE;  // 2097152
#define MROWS 8192  // BB*SSEQ

typedef short short8v __attribute__((ext_vector_type(8)));
typedef float f32x4 __attribute__((ext_vector_type(4)));

__device__ __forceinline__ short f2bf(float x) {
    union { float f; unsigned int u; } v; v.f = x;
    unsigned int u = v.u + 0x7FFFu + ((v.u >> 16) & 1u);
    return (short)(u >> 16);
}
__device__ __forceinline__ short8v cvt8(const float4 a, const float4 b) {
    short8v r;
    r[0] = f2bf(a.x); r[1] = f2bf(a.y); r[2] = f2bf(a.z); r[3] = f2bf(a.w);
    r[4] = f2bf(b.x); r[5] = f2bf(b.y); r[6] = f2bf(b.z); r[7] = f2bf(b.w);
    return r;
}

// ---------------- weights: fp32 [K][N] -> bf16 transposed [N][K] ----------------
__global__ __launch_bounds__(256) void convert_weights(
    const float* __restrict__ W0, const float* __restrict__ W1,
    const float* __restrict__ W2, const float* __restrict__ W3,
    const float* __restrict__ W4,
    unsigned short* __restrict__ T0, unsigned short* __restrict__ T1,
    unsigned short* __restrict__ T2, unsigned short* __restrict__ T3,
    unsigned short* __restrict__ T4)
{
    __shared__ float tile[64][65];
    const int n0 = (blockIdx.x & 7) * 64, k0 = (blockIdx.x >> 3) * 64;
    const float* srcs[5] = {W0, W1, W2, W3, W4};
    unsigned short* dsts[5] = {T0, T1, T2, T3, T4};
    #pragma unroll
    for (int m = 0; m < 5; ++m) {
        const float* W = srcs[m];
        unsigned short* T = dsts[m];
        for (int it = 0; it < 16; ++it) {
            const int idx = it * 256 + threadIdx.x;
            const int r = idx >> 6, c = idx & 63;
            tile[r][c] = W[(size_t)(k0 + r) * DDIM + n0 + c];
        }
        __syncthreads();
        for (int it = 0; it < 16; ++it) {
            const int idx = it * 256 + threadIdx.x;
            const int r = idx >> 6, c = idx & 63;
            T[(size_t)(n0 + r) * DDIM + k0 + c] = (unsigned short)f2bf(tile[c][r]);
        }
        __syncthreads();
    }
}

// ---------------- complex MFMA GEMM: C[M,512] = A[M,512] @ W[512,512] ----------------
// A fp32 (converted in staging), W bf16 transposed [N][K]. 128x128 tile, BK=32.
template <bool LIND>
__global__ __launch_bounds__(256, 1) void cgemm_mfma(
    const float* __restrict__ Ar, const float* __restrict__ Ai,
    const unsigned short* __restrict__ WTr, const unsigned short* __restrict__ WTi,
    const float* __restrict__ Lr, const float* __restrict__ Li,
    float* __restrict__ Cr, float* __restrict__ Ci)
{
    __shared__ unsigned short Ar_s[128 * 32], Ai_s[128 * 32];
    __shared__ unsigned short Br_s[128 * 32], Bi_s[128 * 32];
    const int tid = threadIdx.x;
    const int lane = tid & 63, wave = tid >> 6;
    const int wm = wave >> 1, wn = wave & 1;
    const int col0 = blockIdx.x * 128;
    const int row0 = blockIdx.y * 128;
    const int srow = tid >> 1;   // 0..127
    const int skh = tid & 1;     // k half (16 elems each)

    f32x4 accr[4][4], acci[4][4];
    #pragma unroll
    for (int a = 0; a < 4; ++a)
        #pragma unroll
        for (int b = 0; b < 4; ++b) { accr[a][b] = (f32x4)0.f; acci[a][b] = (f32x4)0.f; }

    for (int k0 = 0; k0 < DDIM; k0 += 32) {
        // stage A (fp32 -> bf16)
        {
            const size_t ab = (size_t)(row0 + srow) * DDIM + k0 + skh * 16;
            const float4 r0 = *reinterpret_cast<const float4*>(Ar + ab);
            const float4 r1 = *reinterpret_cast<const float4*>(Ar + ab + 4);
            const float4 r2 = *reinterpret_cast<const float4*>(Ar + ab + 8);
            const float4 r3 = *reinterpret_cast<const float4*>(Ar + ab + 12);
            const float4 i0 = *reinterpret_cast<const float4*>(Ai + ab);
            const float4 i1 = *reinterpret_cast<const float4*>(Ai + ab + 4);
            const float4 i2 = *reinterpret_cast<const float4*>(Ai + ab + 8);
            const float4 i3 = *reinterpret_cast<const float4*>(Ai + ab + 12);
            const int sw = (srow >> 1) & 3;
            const int ks0 = skh * 2, ks1 = skh * 2 + 1;
            const int ix0 = srow * 32 + ((ks0 ^ sw) << 3);
            const int ix1 = srow * 32 + ((ks1 ^ sw) << 3);
            *reinterpret_cast<short8v*>(&Ar_s[ix0]) = cvt8(r0, r1);
            *reinterpret_cast<short8v*>(&Ar_s[ix1]) = cvt8(r2, r3);
            *reinterpret_cast<short8v*>(&Ai_s[ix0]) = cvt8(i0, i1);
            *reinterpret_cast<short8v*>(&Ai_s[ix1]) = cvt8(i2, i3);
            // stage W (already bf16, [N][K])
            const size_t wb = (size_t)(col0 + srow) * DDIM + k0 + skh * 16;
            const short8v wr0 = *reinterpret_cast<const short8v*>(WTr + wb);
            const short8v wr1 = *reinterpret_cast<const short8v*>(WTr + wb + 8);
            const short8v wi0 = *reinterpret_cast<const short8v*>(WTi + wb);
            const short8v wi1 = *reinterpret_cast<const short8v*>(WTi + wb + 8);
            *reinterpret_cast<short8v*>(&Br_s[ix0]) = wr0;
            *reinterpret_cast<short8v*>(&Br_s[ix1]) = wr1;
            *reinterpret_cast<short8v*>(&Bi_s[ix0]) = wi0;
            *reinterpret_cast<short8v*>(&Bi_s[ix1]) = wi1;
        }
        __syncthreads();
        short8v ar[4], ai[4], ain[4], wr[4], wi[4];
        const int ks = lane >> 4;
        #pragma unroll
        for (int mi = 0; mi < 4; ++mi) {
            const int r = wm * 64 + mi * 16 + (lane & 15);
            const int idx = r * 32 + ((ks ^ ((r >> 1) & 3)) << 3);
            ar[mi] = *reinterpret_cast<const short8v*>(&Ar_s[idx]);
            ai[mi] = *reinterpret_cast<const short8v*>(&Ai_s[idx]);
            #pragma unroll
            for (int j = 0; j < 8; ++j) ain[mi][j] = ai[mi][j] ^ (short)0x8000;
        }
        #pragma unroll
        for (int nj = 0; nj < 4; ++nj) {
            const int n = wn * 64 + nj * 16 + (lane & 15);
            const int idx = n * 32 + ((ks ^ ((n >> 1) & 3)) << 3);
            wr[nj] = *reinterpret_cast<const short8v*>(&Br_s[idx]);
            wi[nj] = *reinterpret_cast<const short8v*>(&Bi_s[idx]);
        }
        #pragma unroll
        for (int mi = 0; mi < 4; ++mi)
            #pragma unroll
            for (int nj = 0; nj < 4; ++nj) {
                accr[mi][nj] = __builtin_amdgcn_mfma_f32_16x16x32_bf16(ar[mi], wr[nj], accr[mi][nj], 0, 0, 0);
                accr[mi][nj] = __builtin_amdgcn_mfma_f32_16x16x32_bf16(ain[mi], wi[nj], accr[mi][nj], 0, 0, 0);
                acci[mi][nj] = __builtin_amdgcn_mfma_f32_16x16x32_bf16(ar[mi], wi[nj], acci[mi][nj], 0, 0, 0);
                acci[mi][nj] = __builtin_amdgcn_mfma_f32_16x16x32_bf16(ai[mi], wr[nj], acci[mi][nj], 0, 0, 0);
            }
        __syncthreads();
    }
    // epilogue
    float lindv[4] = {1.f, 1.f, 1.f, 1.f};
    if (LIND) {
        #pragma unroll
        for (int nj = 0; nj < 4; ++nj) {
            const int col = col0 + wn * 64 + nj * 16 + (lane & 15);
            float s = 0.f;
            #pragma unroll
            for (int k = 0; k < NOPS_; ++k) {
                const float lr = Lr[k * DDIM + col], li = Li[k * DDIM + col];
                s += lr * lr + li * li;
            }
            lindv[nj] = 1.0f - GAMMA_ * s;
        }
    }
    #pragma unroll
    for (int mi = 0; mi < 4; ++mi)
        #pragma unroll
        for (int nj = 0; nj < 4; ++nj) {
            const int col = col0 + wn * 64 + nj * 16 + (lane & 15);
            #pragma unroll
            for (int rr = 0; rr < 4; ++rr) {
                const int row = row0 + wm * 64 + mi * 16 + (lane >> 4) * 4 + rr;
                Cr[(size_t)row * DDIM + col] = accr[mi][nj][rr] * lindv[nj];
                Ci[(size_t)row * DDIM + col] = acci[mi][nj][rr] * lindv[nj];
            }
        }
}

// ---------------- real MFMA GEMM for dt: softplus(A@W + b) ----------------
__global__ __launch_bounds__(256, 1) void rgemm_dt_mfma(
    const float* __restrict__ A, const unsigned short* __restrict__ WT,
    const float* __restrict__ bias, float* __restrict__ Out)
{
    __shared__ unsigned short A_s[128 * 32], B_s[128 * 32];
    const int tid = threadIdx.x;
    const int lane = tid & 63, wave = tid >> 6;
    const int wm = wave >> 1, wn = wave & 1;
    const int col0 = blockIdx.x * 128;
    const int row0 = blockIdx.y * 128;
    const int srow = tid >> 1, skh = tid & 1;

    f32x4 acc[4][4];
    #pragma unroll
    for (int a = 0; a < 4; ++a)
        #pragma unroll
        for (int b = 0; b < 4; ++b) acc[a][b] = (f32x4)0.f;

    for (int k0 = 0; k0 < DDIM; k0 += 32) {
        {
            const size_t ab = (size_t)(row0 + srow) * DDIM + k0 + skh * 16;
            const float4 r0 = *reinterpret_cast<const float4*>(A + ab);
            const float4 r1 = *reinterpret_cast<const float4*>(A + ab + 4);
            const float4 r2 = *reinterpret_cast<const float4*>(A + ab + 8);
            const float4 r3 = *reinterpret_cast<const float4*>(A + ab + 12);
            const int sw = (srow >> 1) & 3;
            const int ix0 = srow * 32 + (((skh * 2) ^ sw) << 3);
            const int ix1 = srow * 32 + (((skh * 2 + 1) ^ sw) << 3);
            *reinterpret_cast<short8v*>(&A_s[ix0]) = cvt8(r0, r1);
            *reinterpret_cast<short8v*>(&A_s[ix1]) = cvt8(r2, r3);
            const size_t wb = (size_t)(col0 + srow) * DDIM + k0 + skh * 16;
            *reinterpret_cast<short8v*>(&B_s[ix0]) = *reinterpret_cast<const short8v*>(WT + wb);
            *reinterpret_cast<short8v*>(&B_s[ix1]) = *reinterpret_cast<const short8v*>(WT + wb + 8);
        }
        __syncthreads();
        short8v av[4], bv[4];
        const int ks = lane >> 4;
        #pragma unroll
        for (int mi = 0; mi < 4; ++mi) {
            const int r = wm * 64 + mi * 16 + (lane & 15);
            av[mi] = *reinterpret_cast<const short8v*>(&A_s[r * 32 + ((ks ^ ((r >> 1) & 3)) << 3)]);
        }
        #pragma unroll
        for (int nj = 0; nj < 4; ++nj) {
            const int n = wn * 64 + nj * 16 + (lane & 15);
            bv[nj] = *reinterpret_cast<const short8v*>(&B_s[n * 32 + ((ks ^ ((n >> 1) & 3)) << 3)]);
        }
        #pragma unroll
        for (int mi = 0; mi < 4; ++mi)
            #pragma unroll
            for (int nj = 0; nj < 4; ++nj)
                acc[mi][nj] = __builtin_amdgcn_mfma_f32_16x16x32_bf16(av[mi], bv[nj], acc[mi][nj], 0, 0, 0);
        __syncthreads();
    }
    #pragma unroll
    for (int mi = 0; mi < 4; ++mi)
        #pragma unroll
        for (int nj = 0; nj < 4; ++nj) {
            const int col = col0 + wn * 64 + nj * 16 + (lane & 15);
            const float bz = bias[col];
            #pragma unroll
            for (int rr = 0; rr < 4; ++rr) {
                const int row = row0 + wm * 64 + mi * 16 + (lane >> 4) * 4 + rr;
                const float z = acc[mi][nj][rr] + bz;
                Out[(size_t)row * DDIM + col] = (z > 0.f) ? (z + log1pf(expf(-z))) : log1pf(expf(z));
            }
        }
}

// ---------------- causal depthwise conv + modSiLU gate ----------------
__global__ __launch_bounds__(256) void conv_gate_kernel(
    const float* __restrict__ ur, const float* __restrict__ ui,
    const float* __restrict__ w, float* __restrict__ gr, float* __restrict__ gi)
{
    const size_t idx = (size_t)blockIdx.x * 256 + threadIdx.x;  // < BSD
    const int d = (int)(idx % DDIM);
    const int s = (int)((idx / DDIM) % SSEQ);
    float ar = 0.f, ai = 0.f;
    #pragma unroll
    for (int k = 0; k < KCONV; ++k) {
        const int soff = s + k - (KCONV - 1);
        if (soff >= 0) {
            const size_t j = idx + (size_t)((long)(k - (KCONV - 1)) * DDIM);
            const float wk = w[k * DDIM + d];
            ar += wk * ur[j];
            ai += wk * ui[j];
        }
    }
    const float mag = sqrtf(ar * ar + ai * ai);
    const float sig = 1.0f / (1.0f + expf(-mag));
    gr[idx] = ar * sig;
    gi[idx] = ai * sig;
}

// ---------------- skinny B/C projections: [8192,512] @ [512,16] ----------------
__global__ __launch_bounds__(256) void bc_kernel(
    const float* __restrict__ xr, const float* __restrict__ WB,
    const float* __restrict__ WC, float* __restrict__ Bm, float* __restrict__ Cm)
{
    const int gid = blockIdx.x * 256 + threadIdx.x;  // < 131072
    const int row = gid >> 4, n = gid & 15;
    const float* xrow = xr + (size_t)row * DDIM;
    float ab = 0.f, ac = 0.f;
    for (int k = 0; k < DDIM; ++k) {
        const float xv = xrow[k];
        ab += xv * WB[k * NSTATE + n];
        ac += xv * WC[k * NSTATE + n];
    }
    Bm[gid] = ab;
    Cm[gid] = ac;
}

// ---------------- chunked selective scan, phase 1 ----------------
__global__ __launch_bounds__(256) void scan_phase1(
    const float* __restrict__ dt, const float* __restrict__ gr, const float* __restrict__ gi,
    const float* __restrict__ Bm, const float* __restrict__ A_log,
    float* __restrict__ mid_hr, float* __restrict__ mid_hi, float* __restrict__ dtsum)
{
    __shared__ float bm_s[LC * NSTATE];
    const int blk = blockIdx.x;
    const int dblk = blk & 1;
    const int c = (blk >> 1) & (NC - 1);
    const int b = blk >> 7;
    const int tid = threadIdx.x;
    const int d = dblk * 256 + tid;
    const int s0 = c * LC;
    {
        const size_t base = ((size_t)b * SSEQ + s0) * NSTATE;
        bm_s[tid] = Bm[base + tid];
        bm_s[tid + 256] = Bm[base + tid + 256];
    }
    float A_dn[16], hr[16], hi[16];
    #pragma unroll
    for (int n = 0; n < 16; ++n) {
        A_dn[n] = -expf(A_log[d * NSTATE + n]);
        hr[n] = 0.f; hi[n] = 0.f;
    }
    float dts = 0.f;
    __syncthreads();
    const size_t gbase = (size_t)b * SSEQ * DDIM + (size_t)s0 * DDIM + d;
    for (int i = 0; i < LC; ++i) {
        const float dtv = dt[gbase + (size_t)i * DDIM];
        const float ur = gr[gbase + (size_t)i * DDIM];
        const float ui = gi[gbase + (size_t)i * DDIM];
        dts += dtv;
        const float xr = dtv * ur, xi = dtv * ui;
        #pragma unroll
        for (int n = 0; n < 16; ++n) {
            const float a = expf(dtv * A_dn[n]);
            const float bmv = bm_s[i * 16 + n];
            hr[n] = a * hr[n] + xr * bmv;
            hi[n] = a * hi[n] + xi * bmv;
        }
    }
    const size_t mbase = ((size_t)(b * NC + c) * DDIM + d) * NSTATE;
    #pragma unroll
    for (int n = 0; n < 16; ++n) { mid_hr[mbase + n] = hr[n]; mid_hi[mbase + n] = hi[n]; }
    dtsum[(size_t)(b * NC + c) * DDIM + d] = dts;
}

// ---------------- phase 2: combine chunk states ----------------
__global__ __launch_bounds__(256) void scan_phase2(
    const float* __restrict__ mid_hr, const float* __restrict__ mid_hi,
    const float* __restrict__ dtsum, const float* __restrict__ A_log,
    float* __restrict__ hinit_r, float* __restrict__ hinit_i)
{
    const int gid = blockIdx.x * 256 + threadIdx.x;  // < 32768
    const int n = gid & 15;
    const int d = (gid >> 4) & (DDIM - 1);
    const int b = gid >> 13;
    const float A_dn = -expf(A_log[d * NSTATE + n]);
    float hr = 0.f, hi = 0.f;
    for (int c = 0; c < NC; ++c) {
        const size_t cb = (size_t)(b * NC + c) * DDIM + d;
        hinit_r[cb * NSTATE + n] = hr;
        hinit_i[cb * NSTATE + n] = hi;
        const float P = expf(A_dn * dtsum[cb]);
        hr = mid_hr[cb * NSTATE + n] + P * hr;
        hi = mid_hi[cb * NSTATE + n] + P * hi;
    }
}

// ---------------- phase 3: recompute with true init, emit y (+D_skip) ----------------
__global__ __launch_bounds__(256) void scan_phase3(
    const float* __restrict__ dt, const float* __restrict__ gr, const float* __restrict__ gi,
    const float* __restrict__ Bm, const float* __restrict__ Cm,
    const float* __restrict__ A_log, const float* __restrict__ D_skip,
    const float* __restrict__ hinit_r, const float* __restrict__ hinit_i,
    float* __restrict__ yr, float* __restrict__ yi)
{
    __shared__ float bm_s[LC * NSTATE], cm_s[LC * NSTATE];
    const int blk = blockIdx.x;
    const int dblk = blk & 1;
    const int c = (blk >> 1) & (NC - 1);
    const int b = blk >> 7;
    const int tid = threadIdx.x;
    const int d = dblk * 256 + tid;
    const int s0 = c * LC;
    {
        const size_t base = ((size_t)b * SSEQ + s0) * NSTATE;
        bm_s[tid] = Bm[base + tid];
        bm_s[tid + 256] = Bm[base + tid + 256];
        cm_s[tid] = Cm[base + tid];
        cm_s[tid + 256] = Cm[base + tid + 256];
    }
    float A_dn[16], hr[16], hi[16];
    const size_t mbase = ((size_t)(b * NC + c) * DDIM + d) * NSTATE;
    #pragma unroll
    for (int n = 0; n < 16; ++n) {
        A_dn[n] = -expf(A_log[d * NSTATE + n]);
        hr[n] = hinit_r[mbase + n];
        hi[n] = hinit_i[mbase + n];
    }
    const float dsk = D_skip[d];
    __syncthreads();
    const size_t gbase = (size_t)b * SSEQ * DDIM + (size_t)s0 * DDIM + d;
    for (int i = 0; i < LC; ++i) {
        const float dtv = dt[gbase + (size_t)i * DDIM];
        const float ur = gr[gbase + (size_t)i * DDIM];
        const float ui = gi[gbase + (size_t)i * DDIM];
        const float xr = dtv * ur, xi = dtv * ui;
        float accr = dsk * ur, acci = dsk * ui;
        #pragma unroll
        for (int n = 0; n < 16; ++n) {
            const float a = expf(dtv * A_dn[n]);
            const float bmv = bm_s[i * 16 + n], cmv = cm_s[i * 16 + n];
            hr[n] = a * hr[n] + xr * bmv;
            hi[n] = a * hi[n] + xi * bmv;
            accr += hr[n] * cmv;
            acci += hi[n] * cmv;
        }
        yr[gbase + (size_t)i * DDIM] = accr;
        yi[gbase + (size_t)i * DDIM] = acci;
    }
}

// ---------------- diag[b,d] = mean_s |branch|^2 ----------------
__global__ __launch_bounds__(256) void diag_kernel(
    const float* __restrict__ br, const float* __restrict__ bi, float* __restrict__ diag)
{
    const int b = blockIdx.x >> 4;
    const int s0 = (blockIdx.x & 15) * 128;
    const int t = threadIdx.x;
    float a0 = 0.f, a1 = 0.f;
    for (int i = 0; i < 128; ++i) {
        const size_t g = (size_t)b * SSEQ * DDIM + (size_t)(s0 + i) * DDIM;
        const float r0 = br[g + t], i0 = bi[g + t];
        const float r1 = br[g + t + 256], i1 = bi[g + t + 256];
        a0 += r0 * r0 + i0 * i0;
        a1 += r1 * r1 + i1 * i1;
    }
    const float inv = 1.0f / (float)SSEQ;
    atomicAdd(&diag[b * DDIM + t], a0 * inv);
    atomicAdd(&diag[b * DDIM + t + 256], a1 * inv);
}

// ---------------- escape flags + sinkhorn coef + rotation table ----------------
__global__ __launch_bounds__(256) void escape_kernel(
    const float* __restrict__ diag, const float* __restrict__ phi,
    const float* __restrict__ logit, const float* __restrict__ logit_im,
    float* __restrict__ misc, float* __restrict__ rot_r, float* __restrict__ rot_i)
{
    const int tid = threadIdx.x;
    rot_r[tid] = cosf(phi[tid]);
    rot_i[tid] = sinf(phi[tid]);
    rot_r[tid + 256] = cosf(phi[tid + 256]);
    rot_i[tid + 256] = sinf(phi[tid + 256]);
    const int b = tid >> 6, lane = tid & 63;
    float mx = -1e30f, mn = 1e30f;
    for (int j = lane; j < DDIM; j += 64) {
        const float v = diag[b * DDIM + j];
        mx = fmaxf(mx, v);
        mn = fminf(mn, v);
    }
    #pragma unroll
    for (int off = 32; off; off >>= 1) {
        mx = fmaxf(mx, __shfl_xor(mx, off));
        mn = fminf(mn, __shfl_xor(mn, off));
    }
    if (lane == 0) {
        const float cond = mx / (mn + 1e-8f);
        misc[b] = (cond > CONDT_) ? 1.0f : 0.0f;
    }
    if (tid == 0) {
        float M = expf(logit[0] / 0.05f);
        for (int it = 0; it < 10; ++it) { M = M / M; M = M / M; }
        const float im = logit_im[0];
        misc[4] = M * cosf(im);
        misc[5] = M * sinf(im);
    }
}

// ---------------- final combine ----------------
__global__ __launch_bounds__(256) void final_kernel(
    const float* __restrict__ xr, const float* __restrict__ xi,
    const float* __restrict__ br, const float* __restrict__ bi,
    const float* __restrict__ misc, const float* __restrict__ rot_r,
    const float* __restrict__ rot_i, float* __restrict__ out)
{
    const size_t idx = (size_t)blockIdx.x * 256 + threadIdx.x;  // < BSD
    const int d = (int)(idx % DDIM);
    const int b = (int)(idx / ((size_t)SSEQ * DDIM));
    float r = br[idx], im = bi[idx];
    if (misc[b] != 0.0f) {
        const float rr = rot_r[d], ri = rot_i[d];
        const float nr = r * rr - im * ri;
        const float ni = r * ri + im * rr;
        r = nr;
        im = ni;
    }
    r *= SCALE_;
    im *= SCALE_;
    const float cr = misc[4], ci = misc[5];
    const float outr = r * cr - im * ci;
    const float outi = im * cr + r * ci;
    out[idx] = xr[idx] + outr;
    out[BSD + idx] = xi[idx] + outi;
}

extern "C" void kernel_launch(void* const* d_in, const int* in_sizes, int n_in,
                              void* d_out, int out_size, void* d_ws, size_t ws_size,
                              hipStream_t stream)
{
    (void)in_sizes; (void)n_in; (void)out_size; (void)ws_size;
    const float* x_r    = (const float*)d_in[0];
    const float* x_i    = (const float*)d_in[1];
    const float* Win_r  = (const float*)d_in[2];
    const float* Win_i  = (const float*)d_in[3];
    const float* convw  = (const float*)d_in[4];
    const float* W_dt   = (const float*)d_in[5];
    const float* b_dt   = (const float*)d_in[6];
    const float* A_log  = (const float*)d_in[7];
    const float* W_B    = (const float*)d_in[8];
    const float* W_C    = (const float*)d_in[9];
    const float* D_skip = (const float*)d_in[10];
    const float* Wout_r = (const float*)d_in[11];
    const float* Wout_i = (const float*)d_in[12];
    const float* L_r    = (const float*)d_in[13];
    const float* L_i    = (const float*)d_in[14];
    const float* phi    = (const float*)d_in[15];
    const float* hres   = (const float*)d_in[16];
    const float* hresi  = (const float*)d_in[17];
    float* out = (float*)d_out;

    float* f    = (float*)d_ws;
    float* u_r  = f;
    float* u_i  = f + BSD;
    float* g_r  = f + 2 * BSD;
    float* g_i  = f + 3 * BSD;
    float* dt   = f + 4 * BSD;
    float* y_r  = f + 5 * BSD;
    float* y_i  = f + 6 * BSD;
    float* Bm   = f + 7 * BSD;
    float* Cm   = Bm + BSN;
    float* dtsum = Cm + BSN;                       // BB*NC*DDIM = 131072
    float* diag = dtsum + (size_t)BB * NC * DDIM;
    float* misc = diag + (size_t)BB * DDIM;
    float* rot_r = misc + 8;
    float* rot_i = rot_r + DDIM;
    unsigned short* wbase = (unsigned short*)(rot_i + DDIM);
    unsigned short* WinT_r  = wbase;
    unsigned short* WinT_i  = wbase + 1 * 262144;
    unsigned short* WoutT_r = wbase + 2 * 262144;
    unsigned short* WoutT_i = wbase + 3 * 262144;
    unsigned short* WdtT    = wbase + 4 * 262144;
    // scan scratch aliased into dead u buffers
    float* mid_hr  = u_r;
    float* mid_hi  = u_r + MIDSZ;
    float* hinit_r = u_i;
    float* hinit_i = u_i + MIDSZ;
    float* br_r = u_r;   // branch output reuses u after scan scratch is dead
    float* br_i = u_i;

    // 0. weight conversion (fp32 [K][N] -> bf16 [N][K])
    convert_weights<<<64, 256, 0, stream>>>(Win_r, Win_i, Wout_r, Wout_i, W_dt,
                                            WinT_r, WinT_i, WoutT_r, WoutT_i, WdtT);
    // 1. complex in-projection (MFMA)
    cgemm_mfma<false><<<dim3(4, 64), 256, 0, stream>>>(
        x_r, x_i, WinT_r, WinT_i, nullptr, nullptr, u_r, u_i);
    // 2. causal conv + modSiLU gate
    conv_gate_kernel<<<(int)(BSD / 256), 256, 0, stream>>>(u_r, u_i, convw, g_r, g_i);
    // 3. dt projection (MFMA, +bias, softplus)
    rgemm_dt_mfma<<<dim3(4, 64), 256, 0, stream>>>(g_r, WdtT, b_dt, dt);
    // 4. B/C projections
    bc_kernel<<<512, 256, 0, stream>>>(g_r, W_B, W_C, Bm, Cm);
    // 5. chunked selective scan (+ D_skip)
    scan_phase1<<<BB * NC * 2, 256, 0, stream>>>(dt, g_r, g_i, Bm, A_log, mid_hr, mid_hi, dtsum);
    scan_phase2<<<128, 256, 0, stream>>>(mid_hr, mid_hi, dtsum, A_log, hinit_r, hinit_i);
    scan_phase3<<<BB * NC * 2, 256, 0, stream>>>(dt, g_r, g_i, Bm, Cm, A_log, D_skip,
                                                 hinit_r, hinit_i, y_r, y_i);
    // 6. complex out-projection (MFMA, + Lindblad scale)
    cgemm_mfma<true><<<dim3(4, 64), 256, 0, stream>>>(
        y_r, y_i, WoutT_r, WoutT_i, L_r, L_i, br_r, br_i);
    // 7. diag power + escape + coef
    hipMemsetAsync(diag, 0, (size_t)BB * DDIM * sizeof(float), stream);
    diag_kernel<<<64, 256, 0, stream>>>(br_r, br_i, diag);
    escape_kernel<<<1, 256, 0, stream>>>(diag, phi, hres, hresi, misc, rot_r, rot_i);
    // 8. final combine
    final_kernel<<<(int)(BSD / 256), 256, 0, stream>>>(
        x_r, x_i, br_r, br_i, misc, rot_r, rot_i, out);
}

// Round 9
// 413.887 us; speedup vs baseline: 3.6406x; 1.4158x over previous
//
#include <hip/hip_runtime.h>
#include <math.h>

#define BB 4
#define SSEQ 2048
#define DDIM 512
#define NSTATE 16
#define KCONV 4
#define NOPS_ 4
#define GAMMA_ 0.01f
#define CONDT_ 100.0f
#define SCALE_ 1.0f
#define NC 64   // chunks over S
#define LC 32   // steps per chunk
#define NCOLF 576  // fused dt|B|C|pad columns

static const size_t BSD = (size_t)BB * SSEQ * DDIM;    // 4194304
static const size_t BSN = (size_t)BB * SSEQ * NSTATE;  // 131072
static const size_t MIDSZ = (size_t)BB * NC * DDIM * NSTATE;  // 2097152

typedef short short8v __attribute__((ext_vector_type(8)));
typedef float f32x4 __attribute__((ext_vector_type(4)));

__device__ __forceinline__ short f2bf(float x) {
    union { float f; unsigned int u; } v; v.f = x;
    unsigned int u = v.u + 0x7FFFu + ((v.u >> 16) & 1u);
    return (short)(u >> 16);
}
__device__ __forceinline__ short8v cvt8(const float4 a, const float4 b) {
    short8v r;
    r[0] = f2bf(a.x); r[1] = f2bf(a.y); r[2] = f2bf(a.z); r[3] = f2bf(a.w);
    r[4] = f2bf(b.x); r[5] = f2bf(b.y); r[6] = f2bf(b.z); r[7] = f2bf(b.w);
    return r;
}

// ---------------- weights: fp32 [K][N] -> bf16 transposed [N][K] (square 512x512) ----
__global__ __launch_bounds__(256) void convert_weights(
    const float* __restrict__ W0, const float* __restrict__ W1,
    const float* __restrict__ W2, const float* __restrict__ W3,
    const float* __restrict__ W4,
    unsigned short* __restrict__ T0, unsigned short* __restrict__ T1,
    unsigned short* __restrict__ T2, unsigned short* __restrict__ T3,
    unsigned short* __restrict__ T4)
{
    __shared__ float tile[64][65];
    const int n0 = (blockIdx.x & 7) * 64, k0 = (blockIdx.x >> 3) * 64;
    const float* srcs[5] = {W0, W1, W2, W3, W4};
    unsigned short* dsts[5] = {T0, T1, T2, T3, T4};
    #pragma unroll
    for (int m = 0; m < 5; ++m) {
        const float* W = srcs[m];
        unsigned short* T = dsts[m];
        for (int it = 0; it < 16; ++it) {
            const int idx = it * 256 + threadIdx.x;
            const int r = idx >> 6, c = idx & 63;
            tile[r][c] = W[(size_t)(k0 + r) * DDIM + n0 + c];
        }
        __syncthreads();
        for (int it = 0; it < 16; ++it) {
            const int idx = it * 256 + threadIdx.x;
            const int r = idx >> 6, c = idx & 63;
            T[(size_t)(n0 + r) * DDIM + k0 + c] = (unsigned short)f2bf(tile[c][r]);
        }
        __syncthreads();
    }
}

// ---------------- W_B/W_C [512][16] -> rows 512..575 of WdtT ([576][512] bf16) ------
__global__ __launch_bounds__(256) void convert_bc(
    const float* __restrict__ WB, const float* __restrict__ WC,
    unsigned short* __restrict__ WdtT)
{
    const int idx = blockIdx.x * 256 + threadIdx.x;  // < 64*512
    const int r = idx >> 9;        // 0..63
    const int k = idx & 511;
    float v = 0.f;
    if (r < 16) v = WB[(size_t)k * NSTATE + r];
    else if (r < 32) v = WC[(size_t)k * NSTATE + (r - 16)];
    WdtT[(size_t)(512 + r) * DDIM + k] = (unsigned short)f2bf(v);
}

// ---------------- complex MFMA GEMM, 64x64 tile, 4 waves of 32x32 -------------------
template <bool LIND>
__global__ __launch_bounds__(256, 4) void cgemm_mfma(
    const float* __restrict__ Ar, const float* __restrict__ Ai,
    const unsigned short* __restrict__ WTr, const unsigned short* __restrict__ WTi,
    const float* __restrict__ Lr, const float* __restrict__ Li,
    float* __restrict__ Cr, float* __restrict__ Ci)
{
    __shared__ unsigned short Ar_s[64 * 32], Ai_s[64 * 32];
    __shared__ unsigned short Br_s[64 * 32], Bi_s[64 * 32];
    const int tid = threadIdx.x;
    const int lane = tid & 63, wave = tid >> 6;
    const int wm = wave >> 1, wn = wave & 1;
    const int col0 = blockIdx.x * 64;
    const int row0 = blockIdx.y * 64;
    const int srow = tid >> 2;   // 0..63
    const int q = tid & 3;       // 8-float quarter of the 32-K row

    f32x4 accr[2][2], acci[2][2];
    #pragma unroll
    for (int a = 0; a < 2; ++a)
        #pragma unroll
        for (int b = 0; b < 2; ++b) { accr[a][b] = (f32x4)0.f; acci[a][b] = (f32x4)0.f; }

    for (int k0 = 0; k0 < DDIM; k0 += 32) {
        {
            const size_t ab = (size_t)(row0 + srow) * DDIM + k0 + q * 8;
            const float4 r0 = *reinterpret_cast<const float4*>(Ar + ab);
            const float4 r1 = *reinterpret_cast<const float4*>(Ar + ab + 4);
            const float4 i0 = *reinterpret_cast<const float4*>(Ai + ab);
            const float4 i1 = *reinterpret_cast<const float4*>(Ai + ab + 4);
            const int ix = srow * 32 + ((q ^ ((srow >> 1) & 3)) << 3);
            *reinterpret_cast<short8v*>(&Ar_s[ix]) = cvt8(r0, r1);
            *reinterpret_cast<short8v*>(&Ai_s[ix]) = cvt8(i0, i1);
            const size_t wb = (size_t)(col0 + srow) * DDIM + k0 + q * 8;
            *reinterpret_cast<short8v*>(&Br_s[ix]) = *reinterpret_cast<const short8v*>(WTr + wb);
            *reinterpret_cast<short8v*>(&Bi_s[ix]) = *reinterpret_cast<const short8v*>(WTi + wb);
        }
        __syncthreads();
        short8v ar[2], ai[2], ain[2], wr[2], wi[2];
        const int ks = lane >> 4;
        #pragma unroll
        for (int mi = 0; mi < 2; ++mi) {
            const int r = wm * 32 + mi * 16 + (lane & 15);
            const int idx = r * 32 + ((ks ^ ((r >> 1) & 3)) << 3);
            ar[mi] = *reinterpret_cast<const short8v*>(&Ar_s[idx]);
            ai[mi] = *reinterpret_cast<const short8v*>(&Ai_s[idx]);
            #pragma unroll
            for (int j = 0; j < 8; ++j) ain[mi][j] = ai[mi][j] ^ (short)0x8000;
        }
        #pragma unroll
        for (int nj = 0; nj < 2; ++nj) {
            const int n = wn * 32 + nj * 16 + (lane & 15);
            const int idx = n * 32 + ((ks ^ ((n >> 1) & 3)) << 3);
            wr[nj] = *reinterpret_cast<const short8v*>(&Br_s[idx]);
            wi[nj] = *reinterpret_cast<const short8v*>(&Bi_s[idx]);
        }
        #pragma unroll
        for (int mi = 0; mi < 2; ++mi)
            #pragma unroll
            for (int nj = 0; nj < 2; ++nj) {
                accr[mi][nj] = __builtin_amdgcn_mfma_f32_16x16x32_bf16(ar[mi], wr[nj], accr[mi][nj], 0, 0, 0);
                accr[mi][nj] = __builtin_amdgcn_mfma_f32_16x16x32_bf16(ain[mi], wi[nj], accr[mi][nj], 0, 0, 0);
                acci[mi][nj] = __builtin_amdgcn_mfma_f32_16x16x32_bf16(ar[mi], wi[nj], acci[mi][nj], 0, 0, 0);
                acci[mi][nj] = __builtin_amdgcn_mfma_f32_16x16x32_bf16(ai[mi], wr[nj], acci[mi][nj], 0, 0, 0);
            }
        __syncthreads();
    }
    float lindv[2] = {1.f, 1.f};
    if (LIND) {
        #pragma unroll
        for (int nj = 0; nj < 2; ++nj) {
            const int col = col0 + wn * 32 + nj * 16 + (lane & 15);
            float s = 0.f;
            #pragma unroll
            for (int k = 0; k < NOPS_; ++k) {
                const float lr = Lr[k * DDIM + col], li = Li[k * DDIM + col];
                s += lr * lr + li * li;
            }
            lindv[nj] = 1.0f - GAMMA_ * s;
        }
    }
    #pragma unroll
    for (int mi = 0; mi < 2; ++mi)
        #pragma unroll
        for (int nj = 0; nj < 2; ++nj) {
            const int col = col0 + wn * 32 + nj * 16 + (lane & 15);
            #pragma unroll
            for (int rr = 0; rr < 4; ++rr) {
                const int row = row0 + wm * 32 + mi * 16 + (lane >> 4) * 4 + rr;
                Cr[(size_t)row * DDIM + col] = accr[mi][nj][rr] * lindv[nj];
                Ci[(size_t)row * DDIM + col] = acci[mi][nj][rr] * lindv[nj];
            }
        }
}

// ------- fused real MFMA GEMM: [dt(softplus+bias) | Bm | Cm] = g_r @ [Wdt|WB|WC] ------
__global__ __launch_bounds__(256, 4) void rgemm_fused(
    const float* __restrict__ A, const unsigned short* __restrict__ WT,
    const float* __restrict__ bias, float* __restrict__ Out,
    float* __restrict__ Bm, float* __restrict__ Cm)
{
    __shared__ unsigned short A_s[64 * 32], B_s[64 * 32];
    const int tid = threadIdx.x;
    const int lane = tid & 63, wave = tid >> 6;
    const int wm = wave >> 1, wn = wave & 1;
    const int col0 = blockIdx.x * 64;   // 0..512 (9 blocks; cols 512..575 are B|C|pad)
    const int row0 = blockIdx.y * 64;
    const int srow = tid >> 2, q = tid & 3;

    f32x4 acc[2][2];
    #pragma unroll
    for (int a = 0; a < 2; ++a)
        #pragma unroll
        for (int b = 0; b < 2; ++b) acc[a][b] = (f32x4)0.f;

    for (int k0 = 0; k0 < DDIM; k0 += 32) {
        {
            const size_t ab = (size_t)(row0 + srow) * DDIM + k0 + q * 8;
            const float4 r0 = *reinterpret_cast<const float4*>(A + ab);
            const float4 r1 = *reinterpret_cast<const float4*>(A + ab + 4);
            const int ix = srow * 32 + ((q ^ ((srow >> 1) & 3)) << 3);
            *reinterpret_cast<short8v*>(&A_s[ix]) = cvt8(r0, r1);
            const size_t wb = (size_t)(col0 + srow) * DDIM + k0 + q * 8;
            *reinterpret_cast<short8v*>(&B_s[ix]) = *reinterpret_cast<const short8v*>(WT + wb);
        }
        __syncthreads();
        short8v av[2], bv[2];
        const int ks = lane >> 4;
        #pragma unroll
        for (int mi = 0; mi < 2; ++mi) {
            const int r = wm * 32 + mi * 16 + (lane & 15);
            av[mi] = *reinterpret_cast<const short8v*>(&A_s[r * 32 + ((ks ^ ((r >> 1) & 3)) << 3)]);
        }
        #pragma unroll
        for (int nj = 0; nj < 2; ++nj) {
            const int n = wn * 32 + nj * 16 + (lane & 15);
            bv[nj] = *reinterpret_cast<const short8v*>(&B_s[n * 32 + ((ks ^ ((n >> 1) & 3)) << 3)]);
        }
        #pragma unroll
        for (int mi = 0; mi < 2; ++mi)
            #pragma unroll
            for (int nj = 0; nj < 2; ++nj)
                acc[mi][nj] = __builtin_amdgcn_mfma_f32_16x16x32_bf16(av[mi], bv[nj], acc[mi][nj], 0, 0, 0);
        __syncthreads();
    }
    #pragma unroll
    for (int mi = 0; mi < 2; ++mi)
        #pragma unroll
        for (int nj = 0; nj < 2; ++nj) {
            const int col = col0 + wn * 32 + nj * 16 + (lane & 15);
            if (col < 512) {
                const float bz = bias[col];
                #pragma unroll
                for (int rr = 0; rr < 4; ++rr) {
                    const int row = row0 + wm * 32 + mi * 16 + (lane >> 4) * 4 + rr;
                    const float z = acc[mi][nj][rr] + bz;
                    Out[(size_t)row * DDIM + col] = (z > 0.f) ? (z + log1pf(expf(-z))) : log1pf(expf(z));
                }
            } else if (col < 528) {
                #pragma unroll
                for (int rr = 0; rr < 4; ++rr) {
                    const int row = row0 + wm * 32 + mi * 16 + (lane >> 4) * 4 + rr;
                    Bm[(size_t)row * NSTATE + (col - 512)] = acc[mi][nj][rr];
                }
            } else if (col < 544) {
                #pragma unroll
                for (int rr = 0; rr < 4; ++rr) {
                    const int row = row0 + wm * 32 + mi * 16 + (lane >> 4) * 4 + rr;
                    Cm[(size_t)row * NSTATE + (col - 528)] = acc[mi][nj][rr];
                }
            }
        }
}

// ---------------- causal depthwise conv + modSiLU gate ----------------
__global__ __launch_bounds__(256) void conv_gate_kernel(
    const float* __restrict__ ur, const float* __restrict__ ui,
    const float* __restrict__ w, float* __restrict__ gr, float* __restrict__ gi)
{
    const size_t idx = (size_t)blockIdx.x * 256 + threadIdx.x;  // < BSD
    const int d = (int)(idx % DDIM);
    const int s = (int)((idx / DDIM) % SSEQ);
    float ar = 0.f, ai = 0.f;
    #pragma unroll
    for (int k = 0; k < KCONV; ++k) {
        const int soff = s + k - (KCONV - 1);
        if (soff >= 0) {
            const size_t j = idx + (size_t)((long)(k - (KCONV - 1)) * DDIM);
            const float wk = w[k * DDIM + d];
            ar += wk * ur[j];
            ai += wk * ui[j];
        }
    }
    const float mag = sqrtf(ar * ar + ai * ai);
    const float sig = 1.0f / (1.0f + expf(-mag));
    gr[idx] = ar * sig;
    gi[idx] = ai * sig;
}

// ---------------- chunked selective scan, phase 1 ----------------
__global__ __launch_bounds__(256) void scan_phase1(
    const float* __restrict__ dt, const float* __restrict__ gr, const float* __restrict__ gi,
    const float* __restrict__ Bm, const float* __restrict__ A_log,
    float* __restrict__ mid_hr, float* __restrict__ mid_hi, float* __restrict__ dtsum)
{
    __shared__ float bm_s[LC * NSTATE];
    const int blk = blockIdx.x;
    const int dblk = blk & 1;
    const int c = (blk >> 1) & (NC - 1);
    const int b = blk >> 7;
    const int tid = threadIdx.x;
    const int d = dblk * 256 + tid;
    const int s0 = c * LC;
    {
        const size_t base = ((size_t)b * SSEQ + s0) * NSTATE;
        bm_s[tid] = Bm[base + tid];
        bm_s[tid + 256] = Bm[base + tid + 256];
    }
    float A_dn[16], hr[16], hi[16];
    #pragma unroll
    for (int n = 0; n < 16; ++n) {
        A_dn[n] = -expf(A_log[d * NSTATE + n]);
        hr[n] = 0.f; hi[n] = 0.f;
    }
    float dts = 0.f;
    __syncthreads();
    const size_t gbase = (size_t)b * SSEQ * DDIM + (size_t)s0 * DDIM + d;
    for (int i = 0; i < LC; ++i) {
        const float dtv = dt[gbase + (size_t)i * DDIM];
        const float ur = gr[gbase + (size_t)i * DDIM];
        const float ui = gi[gbase + (size_t)i * DDIM];
        dts += dtv;
        const float xr = dtv * ur, xi = dtv * ui;
        #pragma unroll
        for (int n = 0; n < 16; ++n) {
            const float a = expf(dtv * A_dn[n]);
            const float bmv = bm_s[i * 16 + n];
            hr[n] = a * hr[n] + xr * bmv;
            hi[n] = a * hi[n] + xi * bmv;
        }
    }
    const size_t mbase = ((size_t)(b * NC + c) * DDIM + d) * NSTATE;
    #pragma unroll
    for (int n = 0; n < 16; ++n) { mid_hr[mbase + n] = hr[n]; mid_hi[mbase + n] = hi[n]; }
    dtsum[(size_t)(b * NC + c) * DDIM + d] = dts;
}

// ---------------- phase 2: combine chunk states ----------------
__global__ __launch_bounds__(256) void scan_phase2(
    const float* __restrict__ mid_hr, const float* __restrict__ mid_hi,
    const float* __restrict__ dtsum, const float* __restrict__ A_log,
    float* __restrict__ hinit_r, float* __restrict__ hinit_i)
{
    const int gid = blockIdx.x * 256 + threadIdx.x;  // < 32768
    const int n = gid & 15;
    const int d = (gid >> 4) & (DDIM - 1);
    const int b = gid >> 13;
    const float A_dn = -expf(A_log[d * NSTATE + n]);
    float hr = 0.f, hi = 0.f;
    for (int c = 0; c < NC; ++c) {
        const size_t cb = (size_t)(b * NC + c) * DDIM + d;
        hinit_r[cb * NSTATE + n] = hr;
        hinit_i[cb * NSTATE + n] = hi;
        const float P = expf(A_dn * dtsum[cb]);
        hr = mid_hr[cb * NSTATE + n] + P * hr;
        hi = mid_hi[cb * NSTATE + n] + P * hi;
    }
}

// ---------------- phase 3: recompute with true init, emit y (+D_skip) ----------------
__global__ __launch_bounds__(256) void scan_phase3(
    const float* __restrict__ dt, const float* __restrict__ gr, const float* __restrict__ gi,
    const float* __restrict__ Bm, const float* __restrict__ Cm,
    const float* __restrict__ A_log, const float* __restrict__ D_skip,
    const float* __restrict__ hinit_r, const float* __restrict__ hinit_i,
    float* __restrict__ yr, float* __restrict__ yi)
{
    __shared__ float bm_s[LC * NSTATE], cm_s[LC * NSTATE];
    const int blk = blockIdx.x;
    const int dblk = blk & 1;
    const int c = (blk >> 1) & (NC - 1);
    const int b = blk >> 7;
    const int tid = threadIdx.x;
    const int d = dblk * 256 + tid;
    const int s0 = c * LC;
    {
        const size_t base = ((size_t)b * SSEQ + s0) * NSTATE;
        bm_s[tid] = Bm[base + tid];
        bm_s[tid + 256] = Bm[base + tid + 256];
        cm_s[tid] = Cm[base + tid];
        cm_s[tid + 256] = Cm[base + tid + 256];
    }
    float A_dn[16], hr[16], hi[16];
    const size_t mbase = ((size_t)(b * NC + c) * DDIM + d) * NSTATE;
    #pragma unroll
    for (int n = 0; n < 16; ++n) {
        A_dn[n] = -expf(A_log[d * NSTATE + n]);
        hr[n] = hinit_r[mbase + n];
        hi[n] = hinit_i[mbase + n];
    }
    const float dsk = D_skip[d];
    __syncthreads();
    const size_t gbase = (size_t)b * SSEQ * DDIM + (size_t)s0 * DDIM + d;
    for (int i = 0; i < LC; ++i) {
        const float dtv = dt[gbase + (size_t)i * DDIM];
        const float ur = gr[gbase + (size_t)i * DDIM];
        const float ui = gi[gbase + (size_t)i * DDIM];
        const float xr = dtv * ur, xi = dtv * ui;
        float accr = dsk * ur, acci = dsk * ui;
        #pragma unroll
        for (int n = 0; n < 16; ++n) {
            const float a = expf(dtv * A_dn[n]);
            const float bmv = bm_s[i * 16 + n], cmv = cm_s[i * 16 + n];
            hr[n] = a * hr[n] + xr * bmv;
            hi[n] = a * hi[n] + xi * bmv;
            accr += hr[n] * cmv;
            acci += hi[n] * cmv;
        }
        yr[gbase + (size_t)i * DDIM] = accr;
        yi[gbase + (size_t)i * DDIM] = acci;
    }
}

// ---------------- diag[b,d] = mean_s |branch|^2 ----------------
__global__ __launch_bounds__(256) void diag_kernel(
    const float* __restrict__ br, const float* __restrict__ bi, float* __restrict__ diag)
{
    const int b = blockIdx.x >> 4;
    const int s0 = (blockIdx.x & 15) * 128;
    const int t = threadIdx.x;
    float a0 = 0.f, a1 = 0.f;
    for (int i = 0; i < 128; ++i) {
        const size_t g = (size_t)b * SSEQ * DDIM + (size_t)(s0 + i) * DDIM;
        const float r0 = br[g + t], i0 = bi[g + t];
        const float r1 = br[g + t + 256], i1 = bi[g + t + 256];
        a0 += r0 * r0 + i0 * i0;
        a1 += r1 * r1 + i1 * i1;
    }
    const float inv = 1.0f / (float)SSEQ;
    atomicAdd(&diag[b * DDIM + t], a0 * inv);
    atomicAdd(&diag[b * DDIM + t + 256], a1 * inv);
}

// ---------------- escape flags + sinkhorn coef + rotation table ----------------
__global__ __launch_bounds__(256) void escape_kernel(
    const float* __restrict__ diag, const float* __restrict__ phi,
    const float* __restrict__ logit, const float* __restrict__ logit_im,
    float* __restrict__ misc, float* __restrict__ rot_r, float* __restrict__ rot_i)
{
    const int tid = threadIdx.x;
    rot_r[tid] = cosf(phi[tid]);
    rot_i[tid] = sinf(phi[tid]);
    rot_r[tid + 256] = cosf(phi[tid + 256]);
    rot_i[tid + 256] = sinf(phi[tid + 256]);
    const int b = tid >> 6, lane = tid & 63;
    float mx = -1e30f, mn = 1e30f;
    for (int j = lane; j < DDIM; j += 64) {
        const float v = diag[b * DDIM + j];
        mx = fmaxf(mx, v);
        mn = fminf(mn, v);
    }
    #pragma unroll
    for (int off = 32; off; off >>= 1) {
        mx = fmaxf(mx, __shfl_xor(mx, off));
        mn = fminf(mn, __shfl_xor(mn, off));
    }
    if (lane == 0) {
        const float cond = mx / (mn + 1e-8f);
        misc[b] = (cond > CONDT_) ? 1.0f : 0.0f;
    }
    if (tid == 0) {
        float M = expf(logit[0] / 0.05f);
        for (int it = 0; it < 10; ++it) { M = M / M; M = M / M; }
        const float im = logit_im[0];
        misc[4] = M * cosf(im);
        misc[5] = M * sinf(im);
    }
}

// ---------------- final combine ----------------
__global__ __launch_bounds__(256) void final_kernel(
    const float* __restrict__ xr, const float* __restrict__ xi,
    const float* __restrict__ br, const float* __restrict__ bi,
    const float* __restrict__ misc, const float* __restrict__ rot_r,
    const float* __restrict__ rot_i, float* __restrict__ out)
{
    const size_t idx = (size_t)blockIdx.x * 256 + threadIdx.x;  // < BSD
    const int d = (int)(idx % DDIM);
    const int b = (int)(idx / ((size_t)SSEQ * DDIM));
    float r = br[idx], im = bi[idx];
    if (misc[b] != 0.0f) {
        const float rr = rot_r[d], ri = rot_i[d];
        const float nr = r * rr - im * ri;
        const float ni = r * ri + im * rr;
        r = nr;
        im = ni;
    }
    r *= SCALE_;
    im *= SCALE_;
    const float cr = misc[4], ci = misc[5];
    const float outr = r * cr - im * ci;
    const float outi = im * cr + r * ci;
    out[idx] = xr[idx] + outr;
    out[BSD + idx] = xi[idx] + outi;
}

extern "C" void kernel_launch(void* const* d_in, const int* in_sizes, int n_in,
                              void* d_out, int out_size, void* d_ws, size_t ws_size,
                              hipStream_t stream)
{
    (void)in_sizes; (void)n_in; (void)out_size; (void)ws_size;
    const float* x_r    = (const float*)d_in[0];
    const float* x_i    = (const float*)d_in[1];
    const float* Win_r  = (const float*)d_in[2];
    const float* Win_i  = (const float*)d_in[3];
    const float* convw  = (const float*)d_in[4];
    const float* W_dt   = (const float*)d_in[5];
    const float* b_dt   = (const float*)d_in[6];
    const float* A_log  = (const float*)d_in[7];
    const float* W_B    = (const float*)d_in[8];
    const float* W_C    = (const float*)d_in[9];
    const float* D_skip = (const float*)d_in[10];
    const float* Wout_r = (const float*)d_in[11];
    const float* Wout_i = (const float*)d_in[12];
    const float* L_r    = (const float*)d_in[13];
    const float* L_i    = (const float*)d_in[14];
    const float* phi    = (const float*)d_in[15];
    const float* hres   = (const float*)d_in[16];
    const float* hresi  = (const float*)d_in[17];
    float* out = (float*)d_out;

    float* f    = (float*)d_ws;
    float* u_r  = f;
    float* u_i  = f + BSD;
    float* g_r  = f + 2 * BSD;
    float* g_i  = f + 3 * BSD;
    float* dt   = f + 4 * BSD;
    float* y_r  = f + 5 * BSD;
    float* y_i  = f + 6 * BSD;
    float* Bm   = f + 7 * BSD;
    float* Cm   = Bm + BSN;
    float* dtsum = Cm + BSN;                       // BB*NC*DDIM = 131072
    float* diag = dtsum + (size_t)BB * NC * DDIM;
    float* misc = diag + (size_t)BB * DDIM;
    float* rot_r = misc + 8;
    float* rot_i = rot_r + DDIM;
    unsigned short* wbase = (unsigned short*)(rot_i + DDIM);
    unsigned short* WinT_r  = wbase;
    unsigned short* WinT_i  = wbase + 1 * 262144;
    unsigned short* WoutT_r = wbase + 2 * 262144;
    unsigned short* WoutT_i = wbase + 3 * 262144;
    unsigned short* WdtT    = wbase + 4 * 262144;   // [576][512]
    // scan scratch aliased into dead u buffers
    float* mid_hr  = u_r;
    float* mid_hi  = u_r + MIDSZ;
    float* hinit_r = u_i;
    float* hinit_i = u_i + MIDSZ;
    float* br_r = u_r;   // branch output reuses u after scan scratch is dead
    float* br_i = u_i;

    // 0. weight conversion (fp32 [K][N] -> bf16 [N][K]; + B/C strip into WdtT)
    convert_weights<<<64, 256, 0, stream>>>(Win_r, Win_i, Wout_r, Wout_i, W_dt,
                                            WinT_r, WinT_i, WoutT_r, WoutT_i, WdtT);
    convert_bc<<<128, 256, 0, stream>>>(W_B, W_C, WdtT);
    // 1. complex in-projection (MFMA, 64x64 tiles -> 1024 blocks)
    cgemm_mfma<false><<<dim3(8, 128), 256, 0, stream>>>(
        x_r, x_i, WinT_r, WinT_i, nullptr, nullptr, u_r, u_i);
    // 2. causal conv + modSiLU gate
    conv_gate_kernel<<<(int)(BSD / 256), 256, 0, stream>>>(u_r, u_i, convw, g_r, g_i);
    // 3. fused dt + B/C projections (MFMA)
    rgemm_fused<<<dim3(9, 128), 256, 0, stream>>>(g_r, WdtT, b_dt, dt, Bm, Cm);
    // 4. chunked selective scan (+ D_skip)
    scan_phase1<<<BB * NC * 2, 256, 0, stream>>>(dt, g_r, g_i, Bm, A_log, mid_hr, mid_hi, dtsum);
    scan_phase2<<<128, 256, 0, stream>>>(mid_hr, mid_hi, dtsum, A_log, hinit_r, hinit_i);
    scan_phase3<<<BB * NC * 2, 256, 0, stream>>>(dt, g_r, g_i, Bm, Cm, A_log, D_skip,
                                                 hinit_r, hinit_i, y_r, y_i);
    // 5. complex out-projection (MFMA, + Lindblad scale)
    cgemm_mfma<true><<<dim3(8, 128), 256, 0, stream>>>(
        y_r, y_i, WoutT_r, WoutT_i, L_r, L_i, br_r, br_i);
    // 6. diag power + escape + coef
    hipMemsetAsync(diag, 0, (size_t)BB * DDIM * sizeof(float), stream);
    diag_kernel<<<64, 256, 0, stream>>>(br_r, br_i, diag);
    escape_kernel<<<1, 256, 0, stream>>>(diag, phi, hres, hresi, misc, rot_r, rot_i);
    // 7. final combine
    final_kernel<<<(int)(BSD / 256), 256, 0, stream>>>(
        x_r, x_i, br_r, br_i, misc, rot_r, rot_i, out);
}

// Round 11
// 362.655 us; speedup vs baseline: 4.1549x; 1.1413x over previous
//
#include <hip/hip_runtime.h>
#include <math.h>

#define BB 4
#define SSEQ 2048
#define DDIM 512
#define NSTATE 16
#define KCONV 4
#define NOPS_ 4
#define GAMMA_ 0.01f
#define CONDT_ 100.0f
#define SCALE_ 1.0f
#define NC 128  // chunks over S
#define LC 16   // steps per chunk

static const size_t BSD = (size_t)BB * SSEQ * DDIM;    // 4194304
static const size_t BSN = (size_t)BB * SSEQ * NSTATE;  // 131072
static const size_t MIDSZ = (size_t)BB * NC * DDIM * NSTATE;  // 4194304 == BSD

typedef short short8v __attribute__((ext_vector_type(8)));
typedef float f32x4 __attribute__((ext_vector_type(4)));

__device__ __forceinline__ short f2bf(float x) {
    union { float f; unsigned int u; } v; v.f = x;
    unsigned int u = v.u + 0x7FFFu + ((v.u >> 16) & 1u);
    return (short)(u >> 16);
}
__device__ __forceinline__ short8v cvt8(const float4 a, const float4 b) {
    short8v r;
    r[0] = f2bf(a.x); r[1] = f2bf(a.y); r[2] = f2bf(a.z); r[3] = f2bf(a.w);
    r[4] = f2bf(b.x); r[5] = f2bf(b.y); r[6] = f2bf(b.z); r[7] = f2bf(b.w);
    return r;
}

// ---------------- weights: fp32 [K][N] -> bf16 transposed [N][K] (square 512x512) ----
__global__ __launch_bounds__(256) void convert_weights(
    const float* __restrict__ W0, const float* __restrict__ W1,
    const float* __restrict__ W2, const float* __restrict__ W3,
    const float* __restrict__ W4,
    unsigned short* __restrict__ T0, unsigned short* __restrict__ T1,
    unsigned short* __restrict__ T2, unsigned short* __restrict__ T3,
    unsigned short* __restrict__ T4)
{
    __shared__ float tile[64][65];
    const int n0 = (blockIdx.x & 7) * 64, k0 = (blockIdx.x >> 3) * 64;
    const float* srcs[5] = {W0, W1, W2, W3, W4};
    unsigned short* dsts[5] = {T0, T1, T2, T3, T4};
    #pragma unroll
    for (int m = 0; m < 5; ++m) {
        const float* W = srcs[m];
        unsigned short* T = dsts[m];
        for (int it = 0; it < 16; ++it) {
            const int idx = it * 256 + threadIdx.x;
            const int r = idx >> 6, c = idx & 63;
            tile[r][c] = W[(size_t)(k0 + r) * DDIM + n0 + c];
        }
        __syncthreads();
        for (int it = 0; it < 16; ++it) {
            const int idx = it * 256 + threadIdx.x;
            const int r = idx >> 6, c = idx & 63;
            T[(size_t)(n0 + r) * DDIM + k0 + c] = (unsigned short)f2bf(tile[c][r]);
        }
        __syncthreads();
    }
}

// ---------------- W_B/W_C [512][16] -> rows 512..575 of WdtT ([576][512] bf16) ------
__global__ __launch_bounds__(256) void convert_bc(
    const float* __restrict__ WB, const float* __restrict__ WC,
    unsigned short* __restrict__ WdtT)
{
    const int idx = blockIdx.x * 256 + threadIdx.x;  // < 64*512
    const int r = idx >> 9;        // 0..63
    const int k = idx & 511;
    float v = 0.f;
    if (r < 16) v = WB[(size_t)k * NSTATE + r];
    else if (r < 32) v = WC[(size_t)k * NSTATE + (r - 16)];
    WdtT[(size_t)(512 + r) * DDIM + k] = (unsigned short)f2bf(v);
}

// ---------------- complex MFMA GEMM, 64x64 tile, 4 waves of 32x32 -------------------
template <bool LIND>
__global__ __launch_bounds__(256, 4) void cgemm_mfma(
    const float* __restrict__ Ar, const float* __restrict__ Ai,
    const unsigned short* __restrict__ WTr, const unsigned short* __restrict__ WTi,
    const float* __restrict__ Lr, const float* __restrict__ Li,
    float* __restrict__ Cr, float* __restrict__ Ci)
{
    __shared__ unsigned short Ar_s[64 * 32], Ai_s[64 * 32];
    __shared__ unsigned short Br_s[64 * 32], Bi_s[64 * 32];
    const int tid = threadIdx.x;
    const int lane = tid & 63, wave = tid >> 6;
    const int wm = wave >> 1, wn = wave & 1;
    const int col0 = blockIdx.x * 64;
    const int row0 = blockIdx.y * 64;
    const int srow = tid >> 2;   // 0..63
    const int q = tid & 3;       // 8-float quarter of the 32-K row

    f32x4 accr[2][2], acci[2][2];
    #pragma unroll
    for (int a = 0; a < 2; ++a)
        #pragma unroll
        for (int b = 0; b < 2; ++b) { accr[a][b] = (f32x4)0.f; acci[a][b] = (f32x4)0.f; }

    for (int k0 = 0; k0 < DDIM; k0 += 32) {
        {
            const size_t ab = (size_t)(row0 + srow) * DDIM + k0 + q * 8;
            const float4 r0 = *reinterpret_cast<const float4*>(Ar + ab);
            const float4 r1 = *reinterpret_cast<const float4*>(Ar + ab + 4);
            const float4 i0 = *reinterpret_cast<const float4*>(Ai + ab);
            const float4 i1 = *reinterpret_cast<const float4*>(Ai + ab + 4);
            const int ix = srow * 32 + ((q ^ ((srow >> 1) & 3)) << 3);
            *reinterpret_cast<short8v*>(&Ar_s[ix]) = cvt8(r0, r1);
            *reinterpret_cast<short8v*>(&Ai_s[ix]) = cvt8(i0, i1);
            const size_t wb = (size_t)(col0 + srow) * DDIM + k0 + q * 8;
            *reinterpret_cast<short8v*>(&Br_s[ix]) = *reinterpret_cast<const short8v*>(WTr + wb);
            *reinterpret_cast<short8v*>(&Bi_s[ix]) = *reinterpret_cast<const short8v*>(WTi + wb);
        }
        __syncthreads();
        short8v ar[2], ai[2], ain[2], wr[2], wi[2];
        const int ks = lane >> 4;
        #pragma unroll
        for (int mi = 0; mi < 2; ++mi) {
            const int r = wm * 32 + mi * 16 + (lane & 15);
            const int idx = r * 32 + ((ks ^ ((r >> 1) & 3)) << 3);
            ar[mi] = *reinterpret_cast<const short8v*>(&Ar_s[idx]);
            ai[mi] = *reinterpret_cast<const short8v*>(&Ai_s[idx]);
            #pragma unroll
            for (int j = 0; j < 8; ++j) ain[mi][j] = ai[mi][j] ^ (short)0x8000;
        }
        #pragma unroll
        for (int nj = 0; nj < 2; ++nj) {
            const int n = wn * 32 + nj * 16 + (lane & 15);
            const int idx = n * 32 + ((ks ^ ((n >> 1) & 3)) << 3);
            wr[nj] = *reinterpret_cast<const short8v*>(&Br_s[idx]);
            wi[nj] = *reinterpret_cast<const short8v*>(&Bi_s[idx]);
        }
        #pragma unroll
        for (int mi = 0; mi < 2; ++mi)
            #pragma unroll
            for (int nj = 0; nj < 2; ++nj) {
                accr[mi][nj] = __builtin_amdgcn_mfma_f32_16x16x32_bf16(ar[mi], wr[nj], accr[mi][nj], 0, 0, 0);
                accr[mi][nj] = __builtin_amdgcn_mfma_f32_16x16x32_bf16(ain[mi], wi[nj], accr[mi][nj], 0, 0, 0);
                acci[mi][nj] = __builtin_amdgcn_mfma_f32_16x16x32_bf16(ar[mi], wi[nj], acci[mi][nj], 0, 0, 0);
                acci[mi][nj] = __builtin_amdgcn_mfma_f32_16x16x32_bf16(ai[mi], wr[nj], acci[mi][nj], 0, 0, 0);
            }
        __syncthreads();
    }
    float lindv[2] = {1.f, 1.f};
    if (LIND) {
        #pragma unroll
        for (int nj = 0; nj < 2; ++nj) {
            const int col = col0 + wn * 32 + nj * 16 + (lane & 15);
            float s = 0.f;
            #pragma unroll
            for (int k = 0; k < NOPS_; ++k) {
                const float lr = Lr[k * DDIM + col], li = Li[k * DDIM + col];
                s += lr * lr + li * li;
            }
            lindv[nj] = 1.0f - GAMMA_ * s;
        }
    }
    #pragma unroll
    for (int mi = 0; mi < 2; ++mi)
        #pragma unroll
        for (int nj = 0; nj < 2; ++nj) {
            const int col = col0 + wn * 32 + nj * 16 + (lane & 15);
            #pragma unroll
            for (int rr = 0; rr < 4; ++rr) {
                const int row = row0 + wm * 32 + mi * 16 + (lane >> 4) * 4 + rr;
                Cr[(size_t)row * DDIM + col] = accr[mi][nj][rr] * lindv[nj];
                Ci[(size_t)row * DDIM + col] = acci[mi][nj][rr] * lindv[nj];
            }
        }
}

// ------- fused real MFMA GEMM: [dt(softplus+bias) | Bm | Cm] = g_r @ [Wdt|WB|WC] ------
__global__ __launch_bounds__(256, 4) void rgemm_fused(
    const float* __restrict__ A, const unsigned short* __restrict__ WT,
    const float* __restrict__ bias, float* __restrict__ Out,
    float* __restrict__ Bm, float* __restrict__ Cm)
{
    __shared__ unsigned short A_s[64 * 32], B_s[64 * 32];
    const int tid = threadIdx.x;
    const int lane = tid & 63, wave = tid >> 6;
    const int wm = wave >> 1, wn = wave & 1;
    const int col0 = blockIdx.x * 64;   // 0..512 (9 blocks; cols 512..575 are B|C|pad)
    const int row0 = blockIdx.y * 64;
    const int srow = tid >> 2, q = tid & 3;

    f32x4 acc[2][2];
    #pragma unroll
    for (int a = 0; a < 2; ++a)
        #pragma unroll
        for (int b = 0; b < 2; ++b) acc[a][b] = (f32x4)0.f;

    for (int k0 = 0; k0 < DDIM; k0 += 32) {
        {
            const size_t ab = (size_t)(row0 + srow) * DDIM + k0 + q * 8;
            const float4 r0 = *reinterpret_cast<const float4*>(A + ab);
            const float4 r1 = *reinterpret_cast<const float4*>(A + ab + 4);
            const int ix = srow * 32 + ((q ^ ((srow >> 1) & 3)) << 3);
            *reinterpret_cast<short8v*>(&A_s[ix]) = cvt8(r0, r1);
            const size_t wb = (size_t)(col0 + srow) * DDIM + k0 + q * 8;
            *reinterpret_cast<short8v*>(&B_s[ix]) = *reinterpret_cast<const short8v*>(WT + wb);
        }
        __syncthreads();
        short8v av[2], bv[2];
        const int ks = lane >> 4;
        #pragma unroll
        for (int mi = 0; mi < 2; ++mi) {
            const int r = wm * 32 + mi * 16 + (lane & 15);
            av[mi] = *reinterpret_cast<const short8v*>(&A_s[r * 32 + ((ks ^ ((r >> 1) & 3)) << 3)]);
        }
        #pragma unroll
        for (int nj = 0; nj < 2; ++nj) {
            const int n = wn * 32 + nj * 16 + (lane & 15);
            bv[nj] = *reinterpret_cast<const short8v*>(&B_s[n * 32 + ((ks ^ ((n >> 1) & 3)) << 3)]);
        }
        #pragma unroll
        for (int mi = 0; mi < 2; ++mi)
            #pragma unroll
            for (int nj = 0; nj < 2; ++nj)
                acc[mi][nj] = __builtin_amdgcn_mfma_f32_16x16x32_bf16(av[mi], bv[nj], acc[mi][nj], 0, 0, 0);
        __syncthreads();
    }
    #pragma unroll
    for (int mi = 0; mi < 2; ++mi)
        #pragma unroll
        for (int nj = 0; nj < 2; ++nj) {
            const int col = col0 + wn * 32 + nj * 16 + (lane & 15);
            if (col < 512) {
                const float bz = bias[col];
                #pragma unroll
                for (int rr = 0; rr < 4; ++rr) {
                    const int row = row0 + wm * 32 + mi * 16 + (lane >> 4) * 4 + rr;
                    const float z = acc[mi][nj][rr] + bz;
                    // softplus, fast-math (abs err < 1e-6, fine vs 0.11 threshold)
                    Out[(size_t)row * DDIM + col] =
                        (z > 0.f) ? (z + __logf(1.f + __expf(-z))) : __logf(1.f + __expf(z));
                }
            } else if (col < 528) {
                #pragma unroll
                for (int rr = 0; rr < 4; ++rr) {
                    const int row = row0 + wm * 32 + mi * 16 + (lane >> 4) * 4 + rr;
                    Bm[(size_t)row * NSTATE + (col - 512)] = acc[mi][nj][rr];
                }
            } else if (col < 544) {
                #pragma unroll
                for (int rr = 0; rr < 4; ++rr) {
                    const int row = row0 + wm * 32 + mi * 16 + (lane >> 4) * 4 + rr;
                    Cm[(size_t)row * NSTATE + (col - 528)] = acc[mi][nj][rr];
                }
            }
        }
}

// ---------------- causal depthwise conv + modSiLU gate ----------------
__global__ __launch_bounds__(256) void conv_gate_kernel(
    const float* __restrict__ ur, const float* __restrict__ ui,
    const float* __restrict__ w, float* __restrict__ gr, float* __restrict__ gi)
{
    const size_t idx = (size_t)blockIdx.x * 256 + threadIdx.x;  // < BSD
    const int d = (int)(idx % DDIM);
    const int s = (int)((idx / DDIM) % SSEQ);
    float ar = 0.f, ai = 0.f;
    #pragma unroll
    for (int k = 0; k < KCONV; ++k) {
        const int soff = s + k - (KCONV - 1);
        if (soff >= 0) {
            const size_t j = idx + (size_t)((long)(k - (KCONV - 1)) * DDIM);
            const float wk = w[k * DDIM + d];
            ar += wk * ur[j];
            ai += wk * ui[j];
        }
    }
    const float mag = sqrtf(ar * ar + ai * ai);
    const float sig = 1.0f / (1.0f + __expf(-mag));
    gr[idx] = ar * sig;
    gi[idx] = ai * sig;
}

// ---------------- chunked selective scan, phase 1: local scan from zero --------------
// 1024 blocks (4 b x 128 c x 2 dblk), thread = one d, 16 states in registers.
__global__ __launch_bounds__(256) void scan_phase1(
    const float* __restrict__ dt, const float* __restrict__ gr, const float* __restrict__ gi,
    const float* __restrict__ Bm, const float* __restrict__ A_log,
    float* __restrict__ mid_hr, float* __restrict__ mid_hi, float* __restrict__ dtsum)
{
    __shared__ float bm_s[LC * NSTATE];   // 256
    const int blk = blockIdx.x;
    const int dblk = blk & 1;
    const int c = (blk >> 1) & (NC - 1);
    const int b = blk >> 8;
    const int tid = threadIdx.x;
    const int d = dblk * 256 + tid;
    const int s0 = c * LC;
    bm_s[tid] = Bm[((size_t)b * SSEQ + s0) * NSTATE + tid];
    float A_dn[16], hr[16], hi[16];
    #pragma unroll
    for (int n = 0; n < 16; ++n) {
        A_dn[n] = -__expf(A_log[d * NSTATE + n]);
        hr[n] = 0.f; hi[n] = 0.f;
    }
    float dts = 0.f;
    __syncthreads();
    const size_t gbase = (size_t)b * SSEQ * DDIM + (size_t)s0 * DDIM + d;
    for (int i = 0; i < LC; ++i) {
        const float dtv = dt[gbase + (size_t)i * DDIM];
        const float ur = gr[gbase + (size_t)i * DDIM];
        const float ui = gi[gbase + (size_t)i * DDIM];
        dts += dtv;
        const float xr = dtv * ur, xi = dtv * ui;
        #pragma unroll
        for (int n = 0; n < 16; ++n) {
            const float a = __expf(dtv * A_dn[n]);
            const float bmv = bm_s[i * 16 + n];
            hr[n] = a * hr[n] + xr * bmv;
            hi[n] = a * hi[n] + xi * bmv;
        }
    }
    const size_t mbase = ((size_t)(b * NC + c) * DDIM + d) * NSTATE;
    #pragma unroll
    for (int n = 0; n < 16; ++n) { mid_hr[mbase + n] = hr[n]; mid_hi[mbase + n] = hi[n]; }
    dtsum[(size_t)(b * NC + c) * DDIM + d] = dts;
}

// ---------------- phase 2: combine chunk states IN-PLACE ----------------
// mid[c] on exit holds the INITIAL state for chunk c (prefix of chunks 0..c-1).
// Each thread owns one (b,d,n) — exclusive access, in-place is race-free.
__global__ __launch_bounds__(256) void scan_phase2(
    float* __restrict__ mid_hr, float* __restrict__ mid_hi,
    const float* __restrict__ dtsum, const float* __restrict__ A_log)
{
    const int gid = blockIdx.x * 256 + threadIdx.x;  // < 32768
    const int n = gid & 15;
    const int d = (gid >> 4) & (DDIM - 1);
    const int b = gid >> 13;
    const float A_dn = -__expf(A_log[d * NSTATE + n]);
    float hr = 0.f, hi = 0.f;
    for (int c = 0; c < NC; ++c) {
        const size_t cb = (size_t)(b * NC + c) * DDIM + d;
        const float mr = mid_hr[cb * NSTATE + n];
        const float mi = mid_hi[cb * NSTATE + n];
        mid_hr[cb * NSTATE + n] = hr;     // initial state for chunk c
        mid_hi[cb * NSTATE + n] = hi;
        const float P = __expf(A_dn * dtsum[cb]);
        hr = mr + P * hr;
        hi = mi + P * hi;
    }
}

// ---------------- phase 3: recompute with true init, emit y (+D_skip) ----------------
__global__ __launch_bounds__(256) void scan_phase3(
    const float* __restrict__ dt, const float* __restrict__ gr, const float* __restrict__ gi,
    const float* __restrict__ Bm, const float* __restrict__ Cm,
    const float* __restrict__ A_log, const float* __restrict__ D_skip,
    const float* __restrict__ hinit_r, const float* __restrict__ hinit_i,
    float* __restrict__ yr, float* __restrict__ yi)
{
    __shared__ float bm_s[LC * NSTATE], cm_s[LC * NSTATE];
    const int blk = blockIdx.x;
    const int dblk = blk & 1;
    const int c = (blk >> 1) & (NC - 1);
    const int b = blk >> 8;
    const int tid = threadIdx.x;
    const int d = dblk * 256 + tid;
    const int s0 = c * LC;
    {
        const size_t base = ((size_t)b * SSEQ + s0) * NSTATE;
        bm_s[tid] = Bm[base + tid];
        cm_s[tid] = Cm[base + tid];
    }
    float A_dn[16], hr[16], hi[16];
    const size_t mbase = ((size_t)(b * NC + c) * DDIM + d) * NSTATE;
    #pragma unroll
    for (int n = 0; n < 16; ++n) {
        A_dn[n] = -__expf(A_log[d * NSTATE + n]);
        hr[n] = hinit_r[mbase + n];
        hi[n] = hinit_i[mbase + n];
    }
    const float dsk = D_skip[d];
    __syncthreads();
    const size_t gbase = (size_t)b * SSEQ * DDIM + (size_t)s0 * DDIM + d;
    for (int i = 0; i < LC; ++i) {
        const float dtv = dt[gbase + (size_t)i * DDIM];
        const float ur = gr[gbase + (size_t)i * DDIM];
        const float ui = gi[gbase + (size_t)i * DDIM];
        const float xr = dtv * ur, xi = dtv * ui;
        float accr = dsk * ur, acci = dsk * ui;
        #pragma unroll
        for (int n = 0; n < 16; ++n) {
            const float a = __expf(dtv * A_dn[n]);
            const float bmv = bm_s[i * 16 + n], cmv = cm_s[i * 16 + n];
            hr[n] = a * hr[n] + xr * bmv;
            hi[n] = a * hi[n] + xi * bmv;
            accr += hr[n] * cmv;
            acci += hi[n] * cmv;
        }
        yr[gbase + (size_t)i * DDIM] = accr;
        yi[gbase + (size_t)i * DDIM] = acci;
    }
}

// ---------------- diag[b,d] = mean_s |branch|^2 (256 blocks) ----------------
__global__ __launch_bounds__(256) void diag_kernel(
    const float* __restrict__ br, const float* __restrict__ bi, float* __restrict__ diag)
{
    const int b = blockIdx.x >> 6;
    const int s0 = (blockIdx.x & 63) * 32;
    const int t = threadIdx.x;
    float a0 = 0.f, a1 = 0.f;
    for (int i = 0; i < 32; ++i) {
        const size_t g = (size_t)b * SSEQ * DDIM + (size_t)(s0 + i) * DDIM;
        const float r0 = br[g + t], i0 = bi[g + t];
        const float r1 = br[g + t + 256], i1 = bi[g + t + 256];
        a0 += r0 * r0 + i0 * i0;
        a1 += r1 * r1 + i1 * i1;
    }
    const float inv = 1.0f / (float)SSEQ;
    atomicAdd(&diag[b * DDIM + t], a0 * inv);
    atomicAdd(&diag[b * DDIM + t + 256], a1 * inv);
}

// ---------------- escape flags + sinkhorn coef + rotation table ----------------
__global__ __launch_bounds__(256) void escape_kernel(
    const float* __restrict__ diag, const float* __restrict__ phi,
    const float* __restrict__ logit, const float* __restrict__ logit_im,
    float* __restrict__ misc, float* __restrict__ rot_r, float* __restrict__ rot_i)
{
    const int tid = threadIdx.x;
    rot_r[tid] = cosf(phi[tid]);
    rot_i[tid] = sinf(phi[tid]);
    rot_r[tid + 256] = cosf(phi[tid + 256]);
    rot_i[tid + 256] = sinf(phi[tid + 256]);
    const int b = tid >> 6, lane = tid & 63;
    float mx = -1e30f, mn = 1e30f;
    for (int j = lane; j < DDIM; j += 64) {
        const float v = diag[b * DDIM + j];
        mx = fmaxf(mx, v);
        mn = fminf(mn, v);
    }
    #pragma unroll
    for (int off = 32; off; off >>= 1) {
        mx = fmaxf(mx, __shfl_xor(mx, off));
        mn = fminf(mn, __shfl_xor(mn, off));
    }
    if (lane == 0) {
        const float cond = mx / (mn + 1e-8f);
        misc[b] = (cond > CONDT_) ? 1.0f : 0.0f;
    }
    if (tid == 0) {
        float M = expf(logit[0] / 0.05f);
        for (int it = 0; it < 10; ++it) { M = M / M; M = M / M; }
        const float im = logit_im[0];
        misc[4] = M * cosf(im);
        misc[5] = M * sinf(im);
    }
}

// ---------------- final combine ----------------
__global__ __launch_bounds__(256) void final_kernel(
    const float* __restrict__ xr, const float* __restrict__ xi,
    const float* __restrict__ br, const float* __restrict__ bi,
    const float* __restrict__ misc, const float* __restrict__ rot_r,
    const float* __restrict__ rot_i, float* __restrict__ out)
{
    const size_t idx = (size_t)blockIdx.x * 256 + threadIdx.x;  // < BSD
    const int d = (int)(idx % DDIM);
    const int b = (int)(idx / ((size_t)SSEQ * DDIM));
    float r = br[idx], im = bi[idx];
    if (misc[b] != 0.0f) {
        const float rr = rot_r[d], ri = rot_i[d];
        const float nr = r * rr - im * ri;
        const float ni = r * ri + im * rr;
        r = nr;
        im = ni;
    }
    r *= SCALE_;
    im *= SCALE_;
    const float cr = misc[4], ci = misc[5];
    const float outr = r * cr - im * ci;
    const float outi = im * cr + r * ci;
    out[idx] = xr[idx] + outr;
    out[BSD + idx] = xi[idx] + outi;
}

extern "C" void kernel_launch(void* const* d_in, const int* in_sizes, int n_in,
                              void* d_out, int out_size, void* d_ws, size_t ws_size,
                              hipStream_t stream)
{
    (void)in_sizes; (void)n_in; (void)out_size; (void)ws_size;
    const float* x_r    = (const float*)d_in[0];
    const float* x_i    = (const float*)d_in[1];
    const float* Win_r  = (const float*)d_in[2];
    const float* Win_i  = (const float*)d_in[3];
    const float* convw  = (const float*)d_in[4];
    const float* W_dt   = (const float*)d_in[5];
    const float* b_dt   = (const float*)d_in[6];
    const float* A_log  = (const float*)d_in[7];
    const float* W_B    = (const float*)d_in[8];
    const float* W_C    = (const float*)d_in[9];
    const float* D_skip = (const float*)d_in[10];
    const float* Wout_r = (const float*)d_in[11];
    const float* Wout_i = (const float*)d_in[12];
    const float* L_r    = (const float*)d_in[13];
    const float* L_i    = (const float*)d_in[14];
    const float* phi    = (const float*)d_in[15];
    const float* hres   = (const float*)d_in[16];
    const float* hresi  = (const float*)d_in[17];
    float* out = (float*)d_out;

    float* f    = (float*)d_ws;
    float* u_r  = f;
    float* u_i  = f + BSD;
    float* g_r  = f + 2 * BSD;
    float* g_i  = f + 3 * BSD;
    float* dt   = f + 4 * BSD;
    float* y_r  = f + 5 * BSD;
    float* y_i  = f + 6 * BSD;
    float* Bm   = f + 7 * BSD;
    float* Cm   = Bm + BSN;
    float* dtsum = Cm + BSN;                       // BB*NC*DDIM = 262144
    float* diag = dtsum + (size_t)BB * NC * DDIM;
    float* misc = diag + (size_t)BB * DDIM;
    float* rot_r = misc + 8;
    float* rot_i = rot_r + DDIM;
    unsigned short* wbase = (unsigned short*)(rot_i + DDIM);
    unsigned short* WinT_r  = wbase;
    unsigned short* WinT_i  = wbase + 1 * 262144;
    unsigned short* WoutT_r = wbase + 2 * 262144;
    unsigned short* WoutT_i = wbase + 3 * 262144;
    unsigned short* WdtT    = wbase + 4 * 262144;   // [576][512]
    // scan scratch aliased into dead u buffers (u dead after conv_gate).
    // mid (== hinit after in-place phase2) fills u_r and u_i exactly (MIDSZ == BSD each).
    float* mid_hr  = u_r;
    float* mid_hi  = u_i;
    float* br_r = u_r;   // branch output reuses u after phase3 consumed mid
    float* br_i = u_i;

    // 0. weight conversion (fp32 [K][N] -> bf16 [N][K]; + B/C strip into WdtT)
    convert_weights<<<64, 256, 0, stream>>>(Win_r, Win_i, Wout_r, Wout_i, W_dt,
                                            WinT_r, WinT_i, WoutT_r, WoutT_i, WdtT);
    convert_bc<<<128, 256, 0, stream>>>(W_B, W_C, WdtT);
    // 1. complex in-projection (MFMA, 64x64 tiles -> 1024 blocks)
    cgemm_mfma<false><<<dim3(8, 128), 256, 0, stream>>>(
        x_r, x_i, WinT_r, WinT_i, nullptr, nullptr, u_r, u_i);
    // 2. causal conv + modSiLU gate
    conv_gate_kernel<<<(int)(BSD / 256), 256, 0, stream>>>(u_r, u_i, convw, g_r, g_i);
    // 3. fused dt + B/C projections (MFMA)
    rgemm_fused<<<dim3(9, 128), 256, 0, stream>>>(g_r, WdtT, b_dt, dt, Bm, Cm);
    // 4. chunked selective scan (+ D_skip): 1024-block phases, in-place combine
    scan_phase1<<<BB * NC * 2, 256, 0, stream>>>(dt, g_r, g_i, Bm, A_log, mid_hr, mid_hi, dtsum);
    scan_phase2<<<128, 256, 0, stream>>>(mid_hr, mid_hi, dtsum, A_log);
    scan_phase3<<<BB * NC * 2, 256, 0, stream>>>(dt, g_r, g_i, Bm, Cm, A_log, D_skip,
                                                 mid_hr, mid_hi, y_r, y_i);
    // 5. complex out-projection (MFMA, + Lindblad scale)
    cgemm_mfma<true><<<dim3(8, 128), 256, 0, stream>>>(
        y_r, y_i, WoutT_r, WoutT_i, L_r, L_i, br_r, br_i);
    // 6. diag power + escape + coef
    hipMemsetAsync(diag, 0, (size_t)BB * DDIM * sizeof(float), stream);
    diag_kernel<<<256, 256, 0, stream>>>(br_r, br_i, diag);
    escape_kernel<<<1, 256, 0, stream>>>(diag, phi, hres, hresi, misc, rot_r, rot_i);
    // 7. final combine
    final_kernel<<<(int)(BSD / 256), 256, 0, stream>>>(
        x_r, x_i, br_r, br_i, misc, rot_r, rot_i, out);
}

// Round 15
// 332.605 us; speedup vs baseline: 4.5303x; 1.0903x over previous
//
#include <hip/hip_runtime.h>
#include <math.h>

#define BB 4
#define SSEQ 2048
#define DDIM 512
#define NSTATE 16
#define KCONV 4
#define NOPS_ 4
#define GAMMA_ 0.01f
#define CONDT_ 100.0f
#define SCALE_ 1.0f
#define NC 128  // chunks over S
#define LC 16   // steps per chunk

static const size_t BSD = (size_t)BB * SSEQ * DDIM;    // 4194304
static const size_t BSN = (size_t)BB * SSEQ * NSTATE;  // 131072
static const size_t MIDSZ = (size_t)BB * NC * DDIM * NSTATE;  // 4194304 == BSD

typedef short short8v __attribute__((ext_vector_type(8)));
typedef float f32x4 __attribute__((ext_vector_type(4)));

__device__ __forceinline__ short f2bf(float x) {
    union { float f; unsigned int u; } v; v.f = x;
    unsigned int u = v.u + 0x7FFFu + ((v.u >> 16) & 1u);
    return (short)(u >> 16);
}
__device__ __forceinline__ short8v cvt8(const float4 a, const float4 b) {
    short8v r;
    r[0] = f2bf(a.x); r[1] = f2bf(a.y); r[2] = f2bf(a.z); r[3] = f2bf(a.w);
    r[4] = f2bf(b.x); r[5] = f2bf(b.y); r[6] = f2bf(b.z); r[7] = f2bf(b.w);
    return r;
}

// ---------------- weights: fp32 [K][N] -> bf16 transposed [N][K] (square 512x512) ----
__global__ __launch_bounds__(256) void convert_weights(
    const float* __restrict__ W0, const float* __restrict__ W1,
    const float* __restrict__ W2, const float* __restrict__ W3,
    const float* __restrict__ W4,
    unsigned short* __restrict__ T0, unsigned short* __restrict__ T1,
    unsigned short* __restrict__ T2, unsigned short* __restrict__ T3,
    unsigned short* __restrict__ T4)
{
    __shared__ float tile[64][65];
    const int n0 = (blockIdx.x & 7) * 64, k0 = (blockIdx.x >> 3) * 64;
    const float* srcs[5] = {W0, W1, W2, W3, W4};
    unsigned short* dsts[5] = {T0, T1, T2, T3, T4};
    #pragma unroll
    for (int m = 0; m < 5; ++m) {
        const float* W = srcs[m];
        unsigned short* T = dsts[m];
        for (int it = 0; it < 16; ++it) {
            const int idx = it * 256 + threadIdx.x;
            const int r = idx >> 6, c = idx & 63;
            tile[r][c] = W[(size_t)(k0 + r) * DDIM + n0 + c];
        }
        __syncthreads();
        for (int it = 0; it < 16; ++it) {
            const int idx = it * 256 + threadIdx.x;
            const int r = idx >> 6, c = idx & 63;
            T[(size_t)(n0 + r) * DDIM + k0 + c] = (unsigned short)f2bf(tile[c][r]);
        }
        __syncthreads();
    }
}

// ---------------- W_B/W_C [512][16] -> rows 512..575 of WdtT ([576][512] bf16) ------
__global__ __launch_bounds__(256) void convert_bc(
    const float* __restrict__ WB, const float* __restrict__ WC,
    unsigned short* __restrict__ WdtT)
{
    const int idx = blockIdx.x * 256 + threadIdx.x;  // < 64*512
    const int r = idx >> 9;        // 0..63
    const int k = idx & 511;
    float v = 0.f;
    if (r < 16) v = WB[(size_t)k * NSTATE + r];
    else if (r < 32) v = WC[(size_t)k * NSTATE + (r - 16)];
    WdtT[(size_t)(512 + r) * DDIM + k] = (unsigned short)f2bf(v);
}

// ---------------- complex MFMA GEMM, 64x64 tile, XCD-swizzled 1D grid (1024) --------
// swizzle: XCD k (hw%8==k) executes logical ids [k*128, (k+1)*128) -> all 8 col-blocks
// of a row-tile land on ONE XCD's L2 -> A-tile fetched once per chip instead of 8x.
template <bool LIND>
__global__ __launch_bounds__(256, 4) void cgemm_mfma(
    const float* __restrict__ Ar, const float* __restrict__ Ai,
    const unsigned short* __restrict__ WTr, const unsigned short* __restrict__ WTi,
    const float* __restrict__ Lr, const float* __restrict__ Li,
    float* __restrict__ Cr, float* __restrict__ Ci)
{
    __shared__ unsigned short Ar_s[64 * 32], Ai_s[64 * 32];
    __shared__ unsigned short Br_s[64 * 32], Bi_s[64 * 32];
    const int q8 = (int)(gridDim.x >> 3);                       // 128
    const int lg = (blockIdx.x & 7) * q8 + (blockIdx.x >> 3);   // bijective
    const int col0 = (lg & 7) * 64;
    const int row0 = (lg >> 3) * 64;
    const int tid = threadIdx.x;
    const int lane = tid & 63, wave = tid >> 6;
    const int wm = wave >> 1, wn = wave & 1;
    const int srow = tid >> 2;   // 0..63
    const int q = tid & 3;       // 8-float quarter of the 32-K row

    f32x4 accr[2][2], acci[2][2];
    #pragma unroll
    for (int a = 0; a < 2; ++a)
        #pragma unroll
        for (int b = 0; b < 2; ++b) { accr[a][b] = (f32x4)0.f; acci[a][b] = (f32x4)0.f; }

    for (int k0 = 0; k0 < DDIM; k0 += 32) {
        {
            const size_t ab = (size_t)(row0 + srow) * DDIM + k0 + q * 8;
            const float4 r0 = *reinterpret_cast<const float4*>(Ar + ab);
            const float4 r1 = *reinterpret_cast<const float4*>(Ar + ab + 4);
            const float4 i0 = *reinterpret_cast<const float4*>(Ai + ab);
            const float4 i1 = *reinterpret_cast<const float4*>(Ai + ab + 4);
            const int ix = srow * 32 + ((q ^ ((srow >> 1) & 3)) << 3);
            *reinterpret_cast<short8v*>(&Ar_s[ix]) = cvt8(r0, r1);
            *reinterpret_cast<short8v*>(&Ai_s[ix]) = cvt8(i0, i1);
            const size_t wb = (size_t)(col0 + srow) * DDIM + k0 + q * 8;
            *reinterpret_cast<short8v*>(&Br_s[ix]) = *reinterpret_cast<const short8v*>(WTr + wb);
            *reinterpret_cast<short8v*>(&Bi_s[ix]) = *reinterpret_cast<const short8v*>(WTi + wb);
        }
        __syncthreads();
        short8v ar[2], ai[2], ain[2], wr[2], wi[2];
        const int ks = lane >> 4;
        #pragma unroll
        for (int mi = 0; mi < 2; ++mi) {
            const int r = wm * 32 + mi * 16 + (lane & 15);
            const int idx = r * 32 + ((ks ^ ((r >> 1) & 3)) << 3);
            ar[mi] = *reinterpret_cast<const short8v*>(&Ar_s[idx]);
            ai[mi] = *reinterpret_cast<const short8v*>(&Ai_s[idx]);
            #pragma unroll
            for (int j = 0; j < 8; ++j) ain[mi][j] = ai[mi][j] ^ (short)0x8000;
        }
        #pragma unroll
        for (int nj = 0; nj < 2; ++nj) {
            const int n = wn * 32 + nj * 16 + (lane & 15);
            const int idx = n * 32 + ((ks ^ ((n >> 1) & 3)) << 3);
            wr[nj] = *reinterpret_cast<const short8v*>(&Br_s[idx]);
            wi[nj] = *reinterpret_cast<const short8v*>(&Bi_s[idx]);
        }
        #pragma unroll
        for (int mi = 0; mi < 2; ++mi)
            #pragma unroll
            for (int nj = 0; nj < 2; ++nj) {
                accr[mi][nj] = __builtin_amdgcn_mfma_f32_16x16x32_bf16(ar[mi], wr[nj], accr[mi][nj], 0, 0, 0);
                accr[mi][nj] = __builtin_amdgcn_mfma_f32_16x16x32_bf16(ain[mi], wi[nj], accr[mi][nj], 0, 0, 0);
                acci[mi][nj] = __builtin_amdgcn_mfma_f32_16x16x32_bf16(ar[mi], wi[nj], acci[mi][nj], 0, 0, 0);
                acci[mi][nj] = __builtin_amdgcn_mfma_f32_16x16x32_bf16(ai[mi], wr[nj], acci[mi][nj], 0, 0, 0);
            }
        __syncthreads();
    }
    float lindv[2] = {1.f, 1.f};
    if (LIND) {
        #pragma unroll
        for (int nj = 0; nj < 2; ++nj) {
            const int col = col0 + wn * 32 + nj * 16 + (lane & 15);
            float s = 0.f;
            #pragma unroll
            for (int k = 0; k < NOPS_; ++k) {
                const float lr = Lr[k * DDIM + col], li = Li[k * DDIM + col];
                s += lr * lr + li * li;
            }
            lindv[nj] = 1.0f - GAMMA_ * s;
        }
    }
    #pragma unroll
    for (int mi = 0; mi < 2; ++mi)
        #pragma unroll
        for (int nj = 0; nj < 2; ++nj) {
            const int col = col0 + wn * 32 + nj * 16 + (lane & 15);
            #pragma unroll
            for (int rr = 0; rr < 4; ++rr) {
                const int row = row0 + wm * 32 + mi * 16 + (lane >> 4) * 4 + rr;
                Cr[(size_t)row * DDIM + col] = accr[mi][nj][rr] * lindv[nj];
                Ci[(size_t)row * DDIM + col] = acci[mi][nj][rr] * lindv[nj];
            }
        }
}

// ------- fused real MFMA GEMM: [dt(softplus+bias) | Bm | Cm], XCD-swizzled (1152) ----
__global__ __launch_bounds__(256, 4) void rgemm_fused(
    const float* __restrict__ A, const unsigned short* __restrict__ WT,
    const float* __restrict__ bias, float* __restrict__ Out,
    float* __restrict__ Bm, float* __restrict__ Cm)
{
    __shared__ unsigned short A_s[64 * 32], B_s[64 * 32];
    const int q8 = (int)(gridDim.x >> 3);                       // 144
    const int lg = (blockIdx.x & 7) * q8 + (blockIdx.x >> 3);
    const int col0 = (lg % 9) * 64;   // 9 col-blocks; cols 512..575 are B|C|pad
    const int row0 = (lg / 9) * 64;
    const int tid = threadIdx.x;
    const int lane = tid & 63, wave = tid >> 6;
    const int wm = wave >> 1, wn = wave & 1;
    const int srow = tid >> 2, q = tid & 3;

    f32x4 acc[2][2];
    #pragma unroll
    for (int a = 0; a < 2; ++a)
        #pragma unroll
        for (int b = 0; b < 2; ++b) acc[a][b] = (f32x4)0.f;

    for (int k0 = 0; k0 < DDIM; k0 += 32) {
        {
            const size_t ab = (size_t)(row0 + srow) * DDIM + k0 + q * 8;
            const float4 r0 = *reinterpret_cast<const float4*>(A + ab);
            const float4 r1 = *reinterpret_cast<const float4*>(A + ab + 4);
            const int ix = srow * 32 + ((q ^ ((srow >> 1) & 3)) << 3);
            *reinterpret_cast<short8v*>(&A_s[ix]) = cvt8(r0, r1);
            const size_t wb = (size_t)(col0 + srow) * DDIM + k0 + q * 8;
            *reinterpret_cast<short8v*>(&B_s[ix]) = *reinterpret_cast<const short8v*>(WT + wb);
        }
        __syncthreads();
        short8v av[2], bv[2];
        const int ks = lane >> 4;
        #pragma unroll
        for (int mi = 0; mi < 2; ++mi) {
            const int r = wm * 32 + mi * 16 + (lane & 15);
            av[mi] = *reinterpret_cast<const short8v*>(&A_s[r * 32 + ((ks ^ ((r >> 1) & 3)) << 3)]);
        }
        #pragma unroll
        for (int nj = 0; nj < 2; ++nj) {
            const int n = wn * 32 + nj * 16 + (lane & 15);
            bv[nj] = *reinterpret_cast<const short8v*>(&B_s[n * 32 + ((ks ^ ((n >> 1) & 3)) << 3)]);
        }
        #pragma unroll
        for (int mi = 0; mi < 2; ++mi)
            #pragma unroll
            for (int nj = 0; nj < 2; ++nj)
                acc[mi][nj] = __builtin_amdgcn_mfma_f32_16x16x32_bf16(av[mi], bv[nj], acc[mi][nj], 0, 0, 0);
        __syncthreads();
    }
    #pragma unroll
    for (int mi = 0; mi < 2; ++mi)
        #pragma unroll
        for (int nj = 0; nj < 2; ++nj) {
            const int col = col0 + wn * 32 + nj * 16 + (lane & 15);
            if (col < 512) {
                const float bz = bias[col];
                #pragma unroll
                for (int rr = 0; rr < 4; ++rr) {
                    const int row = row0 + wm * 32 + mi * 16 + (lane >> 4) * 4 + rr;
                    const float z = acc[mi][nj][rr] + bz;
                    Out[(size_t)row * DDIM + col] =
                        (z > 0.f) ? (z + __logf(1.f + __expf(-z))) : __logf(1.f + __expf(z));
                }
            } else if (col < 528) {
                #pragma unroll
                for (int rr = 0; rr < 4; ++rr) {
                    const int row = row0 + wm * 32 + mi * 16 + (lane >> 4) * 4 + rr;
                    Bm[(size_t)row * NSTATE + (col - 512)] = acc[mi][nj][rr];
                }
            } else if (col < 544) {
                #pragma unroll
                for (int rr = 0; rr < 4; ++rr) {
                    const int row = row0 + wm * 32 + mi * 16 + (lane >> 4) * 4 + rr;
                    Cm[(size_t)row * NSTATE + (col - 528)] = acc[mi][nj][rr];
                }
            }
        }
}

// ---------------- causal depthwise conv + modSiLU gate (float4, 4 d per thread) ------
__global__ __launch_bounds__(256) void conv_gate_kernel(
    const float* __restrict__ ur, const float* __restrict__ ui,
    const float* __restrict__ w, float* __restrict__ gr, float* __restrict__ gi)
{
    const size_t idx = ((size_t)blockIdx.x * 256 + threadIdx.x) * 4;  // < BSD, mult of 4
    const int d = (int)(idx % DDIM);
    const int s = (int)((idx / DDIM) % SSEQ);
    float4 ar = {0.f, 0.f, 0.f, 0.f}, ai = {0.f, 0.f, 0.f, 0.f};
    #pragma unroll
    for (int k = 0; k < KCONV; ++k) {
        const int soff = s + k - (KCONV - 1);
        if (soff >= 0) {
            const size_t j = idx + (size_t)((long)(k - (KCONV - 1)) * DDIM);
            const float4 wk = *reinterpret_cast<const float4*>(w + k * DDIM + d);
            const float4 u4 = *reinterpret_cast<const float4*>(ur + j);
            const float4 v4 = *reinterpret_cast<const float4*>(ui + j);
            ar.x += wk.x * u4.x; ar.y += wk.y * u4.y; ar.z += wk.z * u4.z; ar.w += wk.w * u4.w;
            ai.x += wk.x * v4.x; ai.y += wk.y * v4.y; ai.z += wk.z * v4.z; ai.w += wk.w * v4.w;
        }
    }
    float4 go_r, go_i;
    {
        const float m0 = sqrtf(ar.x * ar.x + ai.x * ai.x);
        const float m1 = sqrtf(ar.y * ar.y + ai.y * ai.y);
        const float m2 = sqrtf(ar.z * ar.z + ai.z * ai.z);
        const float m3 = sqrtf(ar.w * ar.w + ai.w * ai.w);
        const float s0 = 1.f / (1.f + __expf(-m0));
        const float s1 = 1.f / (1.f + __expf(-m1));
        const float s2 = 1.f / (1.f + __expf(-m2));
        const float s3 = 1.f / (1.f + __expf(-m3));
        go_r.x = ar.x * s0; go_r.y = ar.y * s1; go_r.z = ar.z * s2; go_r.w = ar.w * s3;
        go_i.x = ai.x * s0; go_i.y = ai.y * s1; go_i.z = ai.z * s2; go_i.w = ai.w * s3;
    }
    *reinterpret_cast<float4*>(gr + idx) = go_r;
    *reinterpret_cast<float4*>(gi + idx) = go_i;
}

// ---------------- chunked selective scan, phase 1: local scan from zero --------------
__global__ __launch_bounds__(256) void scan_phase1(
    const float* __restrict__ dt, const float* __restrict__ gr, const float* __restrict__ gi,
    const float* __restrict__ Bm, const float* __restrict__ A_log,
    float* __restrict__ mid_hr, float* __restrict__ mid_hi, float* __restrict__ dtsum)
{
    __shared__ float bm_s[LC * NSTATE];   // 256
    const int blk = blockIdx.x;
    const int dblk = blk & 1;
    const int c = (blk >> 1) & (NC - 1);
    const int b = blk >> 8;
    const int tid = threadIdx.x;
    const int d = dblk * 256 + tid;
    const int s0 = c * LC;
    bm_s[tid] = Bm[((size_t)b * SSEQ + s0) * NSTATE + tid];
    float A_dn[16], hr[16], hi[16];
    #pragma unroll
    for (int n = 0; n < 16; ++n) {
        A_dn[n] = -__expf(A_log[d * NSTATE + n]);
        hr[n] = 0.f; hi[n] = 0.f;
    }
    float dts = 0.f;
    __syncthreads();
    const size_t gbase = (size_t)b * SSEQ * DDIM + (size_t)s0 * DDIM + d;
    for (int i = 0; i < LC; ++i) {
        const float dtv = dt[gbase + (size_t)i * DDIM];
        const float ur = gr[gbase + (size_t)i * DDIM];
        const float ui = gi[gbase + (size_t)i * DDIM];
        dts += dtv;
        const float xr = dtv * ur, xi = dtv * ui;
        #pragma unroll
        for (int n = 0; n < 16; ++n) {
            const float a = __expf(dtv * A_dn[n]);
            const float bmv = bm_s[i * 16 + n];
            hr[n] = a * hr[n] + xr * bmv;
            hi[n] = a * hi[n] + xi * bmv;
        }
    }
    const size_t mbase = ((size_t)(b * NC + c) * DDIM + d) * NSTATE;
    #pragma unroll
    for (int n = 0; n < 16; ++n) { mid_hr[mbase + n] = hr[n]; mid_hi[mbase + n] = hi[n]; }
    dtsum[(size_t)(b * NC + c) * DDIM + d] = dts;
}

// ---------------- phase 2: combine chunk states IN-PLACE ----------------
__global__ __launch_bounds__(256) void scan_phase2(
    float* __restrict__ mid_hr, float* __restrict__ mid_hi,
    const float* __restrict__ dtsum, const float* __restrict__ A_log)
{
    const int gid = blockIdx.x * 256 + threadIdx.x;  // < 32768
    const int n = gid & 15;
    const int d = (gid >> 4) & (DDIM - 1);
    const int b = gid >> 13;
    const float A_dn = -__expf(A_log[d * NSTATE + n]);
    float hr = 0.f, hi = 0.f;
    for (int c = 0; c < NC; ++c) {
        const size_t cb = (size_t)(b * NC + c) * DDIM + d;
        const float mr = mid_hr[cb * NSTATE + n];
        const float mi = mid_hi[cb * NSTATE + n];
        mid_hr[cb * NSTATE + n] = hr;     // initial state for chunk c
        mid_hi[cb * NSTATE + n] = hi;
        const float P = __expf(A_dn * dtsum[cb]);
        hr = mr + P * hr;
        hi = mi + P * hi;
    }
}

// ---------------- phase 3: recompute with true init, emit y (+D_skip) ----------------
__global__ __launch_bounds__(256) void scan_phase3(
    const float* __restrict__ dt, const float* __restrict__ gr, const float* __restrict__ gi,
    const float* __restrict__ Bm, const float* __restrict__ Cm,
    const float* __restrict__ A_log, const float* __restrict__ D_skip,
    const float* __restrict__ hinit_r, const float* __restrict__ hinit_i,
    float* __restrict__ yr, float* __restrict__ yi)
{
    __shared__ float bm_s[LC * NSTATE], cm_s[LC * NSTATE];
    const int blk = blockIdx.x;
    const int dblk = blk & 1;
    const int c = (blk >> 1) & (NC - 1);
    const int b = blk >> 8;
    const int tid = threadIdx.x;
    const int d = dblk * 256 + tid;
    const int s0 = c * LC;
    {
        const size_t base = ((size_t)b * SSEQ + s0) * NSTATE;
        bm_s[tid] = Bm[base + tid];
        cm_s[tid] = Cm[base + tid];
    }
    float A_dn[16], hr[16], hi[16];
    const size_t mbase = ((size_t)(b * NC + c) * DDIM + d) * NSTATE;
    #pragma unroll
    for (int n = 0; n < 16; ++n) {
        A_dn[n] = -__expf(A_log[d * NSTATE + n]);
        hr[n] = hinit_r[mbase + n];
        hi[n] = hinit_i[mbase + n];
    }
    const float dsk = D_skip[d];
    __syncthreads();
    const size_t gbase = (size_t)b * SSEQ * DDIM + (size_t)s0 * DDIM + d;
    for (int i = 0; i < LC; ++i) {
        const float dtv = dt[gbase + (size_t)i * DDIM];
        const float ur = gr[gbase + (size_t)i * DDIM];
        const float ui = gi[gbase + (size_t)i * DDIM];
        const float xr = dtv * ur, xi = dtv * ui;
        float accr = dsk * ur, acci = dsk * ui;
        #pragma unroll
        for (int n = 0; n < 16; ++n) {
            const float a = __expf(dtv * A_dn[n]);
            const float bmv = bm_s[i * 16 + n], cmv = cm_s[i * 16 + n];
            hr[n] = a * hr[n] + xr * bmv;
            hi[n] = a * hi[n] + xi * bmv;
            accr += hr[n] * cmv;
            acci += hi[n] * cmv;
        }
        yr[gbase + (size_t)i * DDIM] = accr;
        yi[gbase + (size_t)i * DDIM] = acci;
    }
}

// ---------------- diag[b,d] = mean_s |branch|^2 (256 blocks) ----------------
__global__ __launch_bounds__(256) void diag_kernel(
    const float* __restrict__ br, const float* __restrict__ bi, float* __restrict__ diag)
{
    const int b = blockIdx.x >> 6;
    const int s0 = (blockIdx.x & 63) * 32;
    const int t = threadIdx.x;
    float a0 = 0.f, a1 = 0.f;
    for (int i = 0; i < 32; ++i) {
        const size_t g = (size_t)b * SSEQ * DDIM + (size_t)(s0 + i) * DDIM;
        const float r0 = br[g + t], i0 = bi[g + t];
        const float r1 = br[g + t + 256], i1 = bi[g + t + 256];
        a0 += r0 * r0 + i0 * i0;
        a1 += r1 * r1 + i1 * i1;
    }
    const float inv = 1.0f / (float)SSEQ;
    atomicAdd(&diag[b * DDIM + t], a0 * inv);
    atomicAdd(&diag[b * DDIM + t + 256], a1 * inv);
}

// ---------------- escape flags + sinkhorn coef + rotation table ----------------
__global__ __launch_bounds__(256) void escape_kernel(
    const float* __restrict__ diag, const float* __restrict__ phi,
    const float* __restrict__ logit, const float* __restrict__ logit_im,
    float* __restrict__ misc, float* __restrict__ rot_r, float* __restrict__ rot_i)
{
    const int tid = threadIdx.x;
    rot_r[tid] = cosf(phi[tid]);
    rot_i[tid] = sinf(phi[tid]);
    rot_r[tid + 256] = cosf(phi[tid + 256]);
    rot_i[tid + 256] = sinf(phi[tid + 256]);
    const int b = tid >> 6, lane = tid & 63;
    float mx = -1e30f, mn = 1e30f;
    for (int j = lane; j < DDIM; j += 64) {
        const float v = diag[b * DDIM + j];
        mx = fmaxf(mx, v);
        mn = fminf(mn, v);
    }
    #pragma unroll
    for (int off = 32; off; off >>= 1) {
        mx = fmaxf(mx, __shfl_xor(mx, off));
        mn = fminf(mn, __shfl_xor(mn, off));
    }
    if (lane == 0) {
        const float cond = mx / (mn + 1e-8f);
        misc[b] = (cond > CONDT_) ? 1.0f : 0.0f;
    }
    if (tid == 0) {
        float M = expf(logit[0] / 0.05f);
        for (int it = 0; it < 10; ++it) { M = M / M; M = M / M; }
        const float im = logit_im[0];
        misc[4] = M * cosf(im);
        misc[5] = M * sinf(im);
    }
}

// ---------------- final combine (float4) ----------------
__global__ __launch_bounds__(256) void final_kernel(
    const float* __restrict__ xr, const float* __restrict__ xi,
    const float* __restrict__ br, const float* __restrict__ bi,
    const float* __restrict__ misc, const float* __restrict__ rot_r,
    const float* __restrict__ rot_i, float* __restrict__ out)
{
    const size_t idx = ((size_t)blockIdx.x * 256 + threadIdx.x) * 4;  // < BSD
    const int d = (int)(idx % DDIM);
    const int b = (int)(idx / ((size_t)SSEQ * DDIM));
    float4 r = *reinterpret_cast<const float4*>(br + idx);
    float4 im = *reinterpret_cast<const float4*>(bi + idx);
    if (misc[b] != 0.0f) {
        const float4 rr = *reinterpret_cast<const float4*>(rot_r + d);
        const float4 ri = *reinterpret_cast<const float4*>(rot_i + d);
        float4 nr, ni;
        nr.x = r.x * rr.x - im.x * ri.x; ni.x = r.x * ri.x + im.x * rr.x;
        nr.y = r.y * rr.y - im.y * ri.y; ni.y = r.y * ri.y + im.y * rr.y;
        nr.z = r.z * rr.z - im.z * ri.z; ni.z = r.z * ri.z + im.z * rr.z;
        nr.w = r.w * rr.w - im.w * ri.w; ni.w = r.w * ri.w + im.w * rr.w;
        r = nr; im = ni;
    }
    const float cr = misc[4] * SCALE_, ci = misc[5] * SCALE_;
    const float4 x4 = *reinterpret_cast<const float4*>(xr + idx);
    const float4 y4 = *reinterpret_cast<const float4*>(xi + idx);
    float4 o0, o1;
    o0.x = x4.x + r.x * cr - im.x * ci; o1.x = y4.x + im.x * cr + r.x * ci;
    o0.y = x4.y + r.y * cr - im.y * ci; o1.y = y4.y + im.y * cr + r.y * ci;
    o0.z = x4.z + r.z * cr - im.z * ci; o1.z = y4.z + im.z * cr + r.z * ci;
    o0.w = x4.w + r.w * cr - im.w * ci; o1.w = y4.w + im.w * cr + r.w * ci;
    *reinterpret_cast<float4*>(out + idx) = o0;
    *reinterpret_cast<float4*>(out + BSD + idx) = o1;
}

extern "C" void kernel_launch(void* const* d_in, const int* in_sizes, int n_in,
                              void* d_out, int out_size, void* d_ws, size_t ws_size,
                              hipStream_t stream)
{
    (void)in_sizes; (void)n_in; (void)out_size; (void)ws_size;
    const float* x_r    = (const float*)d_in[0];
    const float* x_i    = (const float*)d_in[1];
    const float* Win_r  = (const float*)d_in[2];
    const float* Win_i  = (const float*)d_in[3];
    const float* convw  = (const float*)d_in[4];
    const float* W_dt   = (const float*)d_in[5];
    const float* b_dt   = (const float*)d_in[6];
    const float* A_log  = (const float*)d_in[7];
    const float* W_B    = (const float*)d_in[8];
    const float* W_C    = (const float*)d_in[9];
    const float* D_skip = (const float*)d_in[10];
    const float* Wout_r = (const float*)d_in[11];
    const float* Wout_i = (const float*)d_in[12];
    const float* L_r    = (const float*)d_in[13];
    const float* L_i    = (const float*)d_in[14];
    const float* phi    = (const float*)d_in[15];
    const float* hres   = (const float*)d_in[16];
    const float* hresi  = (const float*)d_in[17];
    float* out = (float*)d_out;

    float* f    = (float*)d_ws;
    float* u_r  = f;
    float* u_i  = f + BSD;
    float* g_r  = f + 2 * BSD;
    float* g_i  = f + 3 * BSD;
    float* dt   = f + 4 * BSD;
    float* y_r  = f + 5 * BSD;
    float* y_i  = f + 6 * BSD;
    float* Bm   = f + 7 * BSD;
    float* Cm   = Bm + BSN;
    float* dtsum = Cm + BSN;                       // BB*NC*DDIM = 262144
    float* diag = dtsum + (size_t)BB * NC * DDIM;
    float* misc = diag + (size_t)BB * DDIM;
    float* rot_r = misc + 8;
    float* rot_i = rot_r + DDIM;
    unsigned short* wbase = (unsigned short*)(rot_i + DDIM);
    unsigned short* WinT_r  = wbase;
    unsigned short* WinT_i  = wbase + 1 * 262144;
    unsigned short* WoutT_r = wbase + 2 * 262144;
    unsigned short* WoutT_i = wbase + 3 * 262144;
    unsigned short* WdtT    = wbase + 4 * 262144;   // [576][512]
    // scan scratch aliased into dead u buffers (u dead after conv_gate).
    float* mid_hr  = u_r;
    float* mid_hi  = u_i;
    float* br_r = u_r;   // branch output reuses u after phase3 consumed mid
    float* br_i = u_i;

    // 0. weight conversion (fp32 [K][N] -> bf16 [N][K]; + B/C strip into WdtT)
    convert_weights<<<64, 256, 0, stream>>>(Win_r, Win_i, Wout_r, Wout_i, W_dt,
                                            WinT_r, WinT_i, WoutT_r, WoutT_i, WdtT);
    convert_bc<<<128, 256, 0, stream>>>(W_B, W_C, WdtT);
    // 1. complex in-projection (MFMA, XCD-swizzled 1024 blocks)
    cgemm_mfma<false><<<1024, 256, 0, stream>>>(
        x_r, x_i, WinT_r, WinT_i, nullptr, nullptr, u_r, u_i);
    // 2. causal conv + modSiLU gate (float4)
    conv_gate_kernel<<<(int)(BSD / 1024), 256, 0, stream>>>(u_r, u_i, convw, g_r, g_i);
    // 3. fused dt + B/C projections (MFMA, XCD-swizzled 1152 blocks)
    rgemm_fused<<<1152, 256, 0, stream>>>(g_r, WdtT, b_dt, dt, Bm, Cm);
    // 4. chunked selective scan (+ D_skip)
    scan_phase1<<<BB * NC * 2, 256, 0, stream>>>(dt, g_r, g_i, Bm, A_log, mid_hr, mid_hi, dtsum);
    scan_phase2<<<128, 256, 0, stream>>>(mid_hr, mid_hi, dtsum, A_log);
    scan_phase3<<<BB * NC * 2, 256, 0, stream>>>(dt, g_r, g_i, Bm, Cm, A_log, D_skip,
                                                 mid_hr, mid_hi, y_r, y_i);
    // 5. complex out-projection (MFMA, + Lindblad scale)
    cgemm_mfma<true><<<1024, 256, 0, stream>>>(
        y_r, y_i, WoutT_r, WoutT_i, L_r, L_i, br_r, br_i);
    // 6. diag power + escape + coef
    hipMemsetAsync(diag, 0, (size_t)BB * DDIM * sizeof(float), stream);
    diag_kernel<<<256, 256, 0, stream>>>(br_r, br_i, diag);
    escape_kernel<<<1, 256, 0, stream>>>(diag, phi, hres, hresi, misc, rot_r, rot_i);
    // 7. final combine (float4)
    final_kernel<<<(int)(BSD / 1024), 256, 0, stream>>>(
        x_r, x_i, br_r, br_i, misc, rot_r, rot_i, out);
}

// Round 16
// 331.370 us; speedup vs baseline: 4.5471x; 1.0037x over previous
//
#include <hip/hip_runtime.h>
#include <math.h>

#define BB 4
#define SSEQ 2048
#define DDIM 512
#define NSTATE 16
#define KCONV 4
#define NOPS_ 4
#define GAMMA_ 0.01f
#define CONDT_ 100.0f
#define SCALE_ 1.0f
#define NC 128  // chunks over S
#define LC 16   // steps per chunk

static const size_t BSD = (size_t)BB * SSEQ * DDIM;    // 4194304
static const size_t BSN = (size_t)BB * SSEQ * NSTATE;  // 131072
static const size_t MIDSZ = (size_t)BB * NC * DDIM * NSTATE;  // 4194304 == BSD

typedef short short8v __attribute__((ext_vector_type(8)));
typedef float f32x4 __attribute__((ext_vector_type(4)));

__device__ __forceinline__ short f2bf(float x) {
    union { float f; unsigned int u; } v; v.f = x;
    unsigned int u = v.u + 0x7FFFu + ((v.u >> 16) & 1u);
    return (short)(u >> 16);
}
__device__ __forceinline__ short8v cvt8(const float4 a, const float4 b) {
    short8v r;
    r[0] = f2bf(a.x); r[1] = f2bf(a.y); r[2] = f2bf(a.z); r[3] = f2bf(a.w);
    r[4] = f2bf(b.x); r[5] = f2bf(b.y); r[6] = f2bf(b.z); r[7] = f2bf(b.w);
    return r;
}

// ---------------- weights: fp32 [K][N] -> bf16 transposed [N][K] (square 512x512) ----
__global__ __launch_bounds__(256) void convert_weights(
    const float* __restrict__ W0, const float* __restrict__ W1,
    const float* __restrict__ W2, const float* __restrict__ W3,
    const float* __restrict__ W4,
    unsigned short* __restrict__ T0, unsigned short* __restrict__ T1,
    unsigned short* __restrict__ T2, unsigned short* __restrict__ T3,
    unsigned short* __restrict__ T4)
{
    __shared__ float tile[64][65];
    const int n0 = (blockIdx.x & 7) * 64, k0 = (blockIdx.x >> 3) * 64;
    const float* srcs[5] = {W0, W1, W2, W3, W4};
    unsigned short* dsts[5] = {T0, T1, T2, T3, T4};
    #pragma unroll
    for (int m = 0; m < 5; ++m) {
        const float* W = srcs[m];
        unsigned short* T = dsts[m];
        for (int it = 0; it < 16; ++it) {
            const int idx = it * 256 + threadIdx.x;
            const int r = idx >> 6, c = idx & 63;
            tile[r][c] = W[(size_t)(k0 + r) * DDIM + n0 + c];
        }
        __syncthreads();
        for (int it = 0; it < 16; ++it) {
            const int idx = it * 256 + threadIdx.x;
            const int r = idx >> 6, c = idx & 63;
            T[(size_t)(n0 + r) * DDIM + k0 + c] = (unsigned short)f2bf(tile[c][r]);
        }
        __syncthreads();
    }
}

// ---------------- W_B/W_C [512][16] -> rows 512..575 of WdtT ([576][512] bf16) ------
__global__ __launch_bounds__(256) void convert_bc(
    const float* __restrict__ WB, const float* __restrict__ WC,
    unsigned short* __restrict__ WdtT)
{
    const int idx = blockIdx.x * 256 + threadIdx.x;  // < 64*512
    const int r = idx >> 9;        // 0..63
    const int k = idx & 511;
    float v = 0.f;
    if (r < 16) v = WB[(size_t)k * NSTATE + r];
    else if (r < 32) v = WC[(size_t)k * NSTATE + (r - 16)];
    WdtT[(size_t)(512 + r) * DDIM + k] = (unsigned short)f2bf(v);
}

// ---------------- complex MFMA GEMM, 64x64 tile, XCD-swizzled, double-buffered -------
// Pipeline: issue tile k+1 global loads BEFORE MFMA on tile k (latency hides under
// compute); cvt+write to LDS[other] after; ONE barrier per K-iteration.
template <bool LIND>
__global__ __launch_bounds__(256, 4) void cgemm_mfma(
    const float* __restrict__ Ar, const float* __restrict__ Ai,
    const unsigned short* __restrict__ WTr, const unsigned short* __restrict__ WTi,
    const float* __restrict__ Lr, const float* __restrict__ Li,
    float* __restrict__ Cr, float* __restrict__ Ci)
{
    __shared__ unsigned short Ar_s[2][64 * 32], Ai_s[2][64 * 32];
    __shared__ unsigned short Br_s[2][64 * 32], Bi_s[2][64 * 32];
    const int q8 = (int)(gridDim.x >> 3);                       // 128
    const int lg = (blockIdx.x & 7) * q8 + (blockIdx.x >> 3);   // bijective
    const int col0 = (lg & 7) * 64;
    const int row0 = (lg >> 3) * 64;
    const int tid = threadIdx.x;
    const int lane = tid & 63, wave = tid >> 6;
    const int wm = wave >> 1, wn = wave & 1;
    const int srow = tid >> 2;   // 0..63
    const int q = tid & 3;       // 8-float quarter of the 32-K row
    const size_t abase = (size_t)(row0 + srow) * DDIM + q * 8;
    const size_t wbase = (size_t)(col0 + srow) * DDIM + q * 8;
    const int ix = srow * 32 + ((q ^ ((srow >> 1) & 3)) << 3);

    f32x4 accr[2][2], acci[2][2];
    #pragma unroll
    for (int a = 0; a < 2; ++a)
        #pragma unroll
        for (int b = 0; b < 2; ++b) { accr[a][b] = (f32x4)0.f; acci[a][b] = (f32x4)0.f; }

    // prologue: stage tile 0 into buffer 0
    {
        const float4 r0 = *reinterpret_cast<const float4*>(Ar + abase);
        const float4 r1 = *reinterpret_cast<const float4*>(Ar + abase + 4);
        const float4 i0 = *reinterpret_cast<const float4*>(Ai + abase);
        const float4 i1 = *reinterpret_cast<const float4*>(Ai + abase + 4);
        *reinterpret_cast<short8v*>(&Ar_s[0][ix]) = cvt8(r0, r1);
        *reinterpret_cast<short8v*>(&Ai_s[0][ix]) = cvt8(i0, i1);
        *reinterpret_cast<short8v*>(&Br_s[0][ix]) = *reinterpret_cast<const short8v*>(WTr + wbase);
        *reinterpret_cast<short8v*>(&Bi_s[0][ix]) = *reinterpret_cast<const short8v*>(WTi + wbase);
    }
    __syncthreads();

    for (int kt = 0; kt < 16; ++kt) {
        const int cur = kt & 1;
        // issue next-tile global loads early (consumed after the MFMAs)
        float4 nr0, nr1, ni0, ni1;
        short8v nwr, nwi;
        if (kt < 15) {
            const size_t ab = abase + (size_t)(kt + 1) * 32;
            nr0 = *reinterpret_cast<const float4*>(Ar + ab);
            nr1 = *reinterpret_cast<const float4*>(Ar + ab + 4);
            ni0 = *reinterpret_cast<const float4*>(Ai + ab);
            ni1 = *reinterpret_cast<const float4*>(Ai + ab + 4);
            const size_t wb = wbase + (size_t)(kt + 1) * 32;
            nwr = *reinterpret_cast<const short8v*>(WTr + wb);
            nwi = *reinterpret_cast<const short8v*>(WTi + wb);
        }
        // compute on LDS[cur]
        short8v ar[2], ai[2], ain[2], wr[2], wi[2];
        const int ks = lane >> 4;
        #pragma unroll
        for (int mi = 0; mi < 2; ++mi) {
            const int r = wm * 32 + mi * 16 + (lane & 15);
            const int idx = r * 32 + ((ks ^ ((r >> 1) & 3)) << 3);
            ar[mi] = *reinterpret_cast<const short8v*>(&Ar_s[cur][idx]);
            ai[mi] = *reinterpret_cast<const short8v*>(&Ai_s[cur][idx]);
            #pragma unroll
            for (int j = 0; j < 8; ++j) ain[mi][j] = ai[mi][j] ^ (short)0x8000;
        }
        #pragma unroll
        for (int nj = 0; nj < 2; ++nj) {
            const int n = wn * 32 + nj * 16 + (lane & 15);
            const int idx = n * 32 + ((ks ^ ((n >> 1) & 3)) << 3);
            wr[nj] = *reinterpret_cast<const short8v*>(&Br_s[cur][idx]);
            wi[nj] = *reinterpret_cast<const short8v*>(&Bi_s[cur][idx]);
        }
        #pragma unroll
        for (int mi = 0; mi < 2; ++mi)
            #pragma unroll
            for (int nj = 0; nj < 2; ++nj) {
                accr[mi][nj] = __builtin_amdgcn_mfma_f32_16x16x32_bf16(ar[mi], wr[nj], accr[mi][nj], 0, 0, 0);
                accr[mi][nj] = __builtin_amdgcn_mfma_f32_16x16x32_bf16(ain[mi], wi[nj], accr[mi][nj], 0, 0, 0);
                acci[mi][nj] = __builtin_amdgcn_mfma_f32_16x16x32_bf16(ar[mi], wi[nj], acci[mi][nj], 0, 0, 0);
                acci[mi][nj] = __builtin_amdgcn_mfma_f32_16x16x32_bf16(ai[mi], wr[nj], acci[mi][nj], 0, 0, 0);
            }
        // write next tile into the other buffer
        if (kt < 15) {
            *reinterpret_cast<short8v*>(&Ar_s[cur ^ 1][ix]) = cvt8(nr0, nr1);
            *reinterpret_cast<short8v*>(&Ai_s[cur ^ 1][ix]) = cvt8(ni0, ni1);
            *reinterpret_cast<short8v*>(&Br_s[cur ^ 1][ix]) = nwr;
            *reinterpret_cast<short8v*>(&Bi_s[cur ^ 1][ix]) = nwi;
        }
        __syncthreads();
    }
    float lindv[2] = {1.f, 1.f};
    if (LIND) {
        #pragma unroll
        for (int nj = 0; nj < 2; ++nj) {
            const int col = col0 + wn * 32 + nj * 16 + (lane & 15);
            float s = 0.f;
            #pragma unroll
            for (int k = 0; k < NOPS_; ++k) {
                const float lr = Lr[k * DDIM + col], li = Li[k * DDIM + col];
                s += lr * lr + li * li;
            }
            lindv[nj] = 1.0f - GAMMA_ * s;
        }
    }
    #pragma unroll
    for (int mi = 0; mi < 2; ++mi)
        #pragma unroll
        for (int nj = 0; nj < 2; ++nj) {
            const int col = col0 + wn * 32 + nj * 16 + (lane & 15);
            #pragma unroll
            for (int rr = 0; rr < 4; ++rr) {
                const int row = row0 + wm * 32 + mi * 16 + (lane >> 4) * 4 + rr;
                Cr[(size_t)row * DDIM + col] = accr[mi][nj][rr] * lindv[nj];
                Ci[(size_t)row * DDIM + col] = acci[mi][nj][rr] * lindv[nj];
            }
        }
}

// ------- fused real MFMA GEMM: [dt|Bm|Cm], XCD-swizzled, double-buffered -------------
__global__ __launch_bounds__(256, 4) void rgemm_fused(
    const float* __restrict__ A, const unsigned short* __restrict__ WT,
    const float* __restrict__ bias, float* __restrict__ Out,
    float* __restrict__ Bm, float* __restrict__ Cm)
{
    __shared__ unsigned short A_s[2][64 * 32], B_s[2][64 * 32];
    const int q8 = (int)(gridDim.x >> 3);                       // 144
    const int lg = (blockIdx.x & 7) * q8 + (blockIdx.x >> 3);
    const int col0 = (lg % 9) * 64;   // 9 col-blocks; cols 512..575 are B|C|pad
    const int row0 = (lg / 9) * 64;
    const int tid = threadIdx.x;
    const int lane = tid & 63, wave = tid >> 6;
    const int wm = wave >> 1, wn = wave & 1;
    const int srow = tid >> 2, q = tid & 3;
    const size_t abase = (size_t)(row0 + srow) * DDIM + q * 8;
    const size_t wbase = (size_t)(col0 + srow) * DDIM + q * 8;
    const int ix = srow * 32 + ((q ^ ((srow >> 1) & 3)) << 3);

    f32x4 acc[2][2];
    #pragma unroll
    for (int a = 0; a < 2; ++a)
        #pragma unroll
        for (int b = 0; b < 2; ++b) acc[a][b] = (f32x4)0.f;

    {
        const float4 r0 = *reinterpret_cast<const float4*>(A + abase);
        const float4 r1 = *reinterpret_cast<const float4*>(A + abase + 4);
        *reinterpret_cast<short8v*>(&A_s[0][ix]) = cvt8(r0, r1);
        *reinterpret_cast<short8v*>(&B_s[0][ix]) = *reinterpret_cast<const short8v*>(WT + wbase);
    }
    __syncthreads();

    for (int kt = 0; kt < 16; ++kt) {
        const int cur = kt & 1;
        float4 nr0, nr1;
        short8v nw;
        if (kt < 15) {
            const size_t ab = abase + (size_t)(kt + 1) * 32;
            nr0 = *reinterpret_cast<const float4*>(A + ab);
            nr1 = *reinterpret_cast<const float4*>(A + ab + 4);
            nw = *reinterpret_cast<const short8v*>(WT + wbase + (size_t)(kt + 1) * 32);
        }
        short8v av[2], bv[2];
        const int ks = lane >> 4;
        #pragma unroll
        for (int mi = 0; mi < 2; ++mi) {
            const int r = wm * 32 + mi * 16 + (lane & 15);
            av[mi] = *reinterpret_cast<const short8v*>(&A_s[cur][r * 32 + ((ks ^ ((r >> 1) & 3)) << 3)]);
        }
        #pragma unroll
        for (int nj = 0; nj < 2; ++nj) {
            const int n = wn * 32 + nj * 16 + (lane & 15);
            bv[nj] = *reinterpret_cast<const short8v*>(&B_s[cur][n * 32 + ((ks ^ ((n >> 1) & 3)) << 3)]);
        }
        #pragma unroll
        for (int mi = 0; mi < 2; ++mi)
            #pragma unroll
            for (int nj = 0; nj < 2; ++nj)
                acc[mi][nj] = __builtin_amdgcn_mfma_f32_16x16x32_bf16(av[mi], bv[nj], acc[mi][nj], 0, 0, 0);
        if (kt < 15) {
            *reinterpret_cast<short8v*>(&A_s[cur ^ 1][ix]) = cvt8(nr0, nr1);
            *reinterpret_cast<short8v*>(&B_s[cur ^ 1][ix]) = nw;
        }
        __syncthreads();
    }
    #pragma unroll
    for (int mi = 0; mi < 2; ++mi)
        #pragma unroll
        for (int nj = 0; nj < 2; ++nj) {
            const int col = col0 + wn * 32 + nj * 16 + (lane & 15);
            if (col < 512) {
                const float bz = bias[col];
                #pragma unroll
                for (int rr = 0; rr < 4; ++rr) {
                    const int row = row0 + wm * 32 + mi * 16 + (lane >> 4) * 4 + rr;
                    const float z = acc[mi][nj][rr] + bz;
                    Out[(size_t)row * DDIM + col] =
                        (z > 0.f) ? (z + __logf(1.f + __expf(-z))) : __logf(1.f + __expf(z));
                }
            } else if (col < 528) {
                #pragma unroll
                for (int rr = 0; rr < 4; ++rr) {
                    const int row = row0 + wm * 32 + mi * 16 + (lane >> 4) * 4 + rr;
                    Bm[(size_t)row * NSTATE + (col - 512)] = acc[mi][nj][rr];
                }
            } else if (col < 544) {
                #pragma unroll
                for (int rr = 0; rr < 4; ++rr) {
                    const int row = row0 + wm * 32 + mi * 16 + (lane >> 4) * 4 + rr;
                    Cm[(size_t)row * NSTATE + (col - 528)] = acc[mi][nj][rr];
                }
            }
        }
}

// ---------------- causal depthwise conv + modSiLU gate (float4, 4 d per thread) ------
__global__ __launch_bounds__(256) void conv_gate_kernel(
    const float* __restrict__ ur, const float* __restrict__ ui,
    const float* __restrict__ w, float* __restrict__ gr, float* __restrict__ gi)
{
    const size_t idx = ((size_t)blockIdx.x * 256 + threadIdx.x) * 4;  // < BSD, mult of 4
    const int d = (int)(idx % DDIM);
    const int s = (int)((idx / DDIM) % SSEQ);
    float4 ar = {0.f, 0.f, 0.f, 0.f}, ai = {0.f, 0.f, 0.f, 0.f};
    #pragma unroll
    for (int k = 0; k < KCONV; ++k) {
        const int soff = s + k - (KCONV - 1);
        if (soff >= 0) {
            const size_t j = idx + (size_t)((long)(k - (KCONV - 1)) * DDIM);
            const float4 wk = *reinterpret_cast<const float4*>(w + k * DDIM + d);
            const float4 u4 = *reinterpret_cast<const float4*>(ur + j);
            const float4 v4 = *reinterpret_cast<const float4*>(ui + j);
            ar.x += wk.x * u4.x; ar.y += wk.y * u4.y; ar.z += wk.z * u4.z; ar.w += wk.w * u4.w;
            ai.x += wk.x * v4.x; ai.y += wk.y * v4.y; ai.z += wk.z * v4.z; ai.w += wk.w * v4.w;
        }
    }
    float4 go_r, go_i;
    {
        const float m0 = sqrtf(ar.x * ar.x + ai.x * ai.x);
        const float m1 = sqrtf(ar.y * ar.y + ai.y * ai.y);
        const float m2 = sqrtf(ar.z * ar.z + ai.z * ai.z);
        const float m3 = sqrtf(ar.w * ar.w + ai.w * ai.w);
        const float s0 = 1.f / (1.f + __expf(-m0));
        const float s1 = 1.f / (1.f + __expf(-m1));
        const float s2 = 1.f / (1.f + __expf(-m2));
        const float s3 = 1.f / (1.f + __expf(-m3));
        go_r.x = ar.x * s0; go_r.y = ar.y * s1; go_r.z = ar.z * s2; go_r.w = ar.w * s3;
        go_i.x = ai.x * s0; go_i.y = ai.y * s1; go_i.z = ai.z * s2; go_i.w = ai.w * s3;
    }
    *reinterpret_cast<float4*>(gr + idx) = go_r;
    *reinterpret_cast<float4*>(gi + idx) = go_i;
}

// ---------------- chunked selective scan, phase 1: local scan from zero --------------
__global__ __launch_bounds__(256) void scan_phase1(
    const float* __restrict__ dt, const float* __restrict__ gr, const float* __restrict__ gi,
    const float* __restrict__ Bm, const float* __restrict__ A_log,
    float* __restrict__ mid_hr, float* __restrict__ mid_hi, float* __restrict__ dtsum)
{
    __shared__ float bm_s[LC * NSTATE];   // 256
    const int blk = blockIdx.x;
    const int dblk = blk & 1;
    const int c = (blk >> 1) & (NC - 1);
    const int b = blk >> 8;
    const int tid = threadIdx.x;
    const int d = dblk * 256 + tid;
    const int s0 = c * LC;
    bm_s[tid] = Bm[((size_t)b * SSEQ + s0) * NSTATE + tid];
    float A_dn[16], hr[16], hi[16];
    #pragma unroll
    for (int n = 0; n < 16; ++n) {
        A_dn[n] = -__expf(A_log[d * NSTATE + n]);
        hr[n] = 0.f; hi[n] = 0.f;
    }
    float dts = 0.f;
    __syncthreads();
    const size_t gbase = (size_t)b * SSEQ * DDIM + (size_t)s0 * DDIM + d;
    for (int i = 0; i < LC; ++i) {
        const float dtv = dt[gbase + (size_t)i * DDIM];
        const float ur = gr[gbase + (size_t)i * DDIM];
        const float ui = gi[gbase + (size_t)i * DDIM];
        dts += dtv;
        const float xr = dtv * ur, xi = dtv * ui;
        #pragma unroll
        for (int n = 0; n < 16; ++n) {
            const float a = __expf(dtv * A_dn[n]);
            const float bmv = bm_s[i * 16 + n];
            hr[n] = a * hr[n] + xr * bmv;
            hi[n] = a * hi[n] + xi * bmv;
        }
    }
    const size_t mbase = ((size_t)(b * NC + c) * DDIM + d) * NSTATE;
    #pragma unroll
    for (int n = 0; n < 16; ++n) { mid_hr[mbase + n] = hr[n]; mid_hi[mbase + n] = hi[n]; }
    dtsum[(size_t)(b * NC + c) * DDIM + d] = dts;
}

// ---------------- phase 2: combine chunk states IN-PLACE ----------------
__global__ __launch_bounds__(256) void scan_phase2(
    float* __restrict__ mid_hr, float* __restrict__ mid_hi,
    const float* __restrict__ dtsum, const float* __restrict__ A_log)
{
    const int gid = blockIdx.x * 256 + threadIdx.x;  // < 32768
    const int n = gid & 15;
    const int d = (gid >> 4) & (DDIM - 1);
    const int b = gid >> 13;
    const float A_dn = -__expf(A_log[d * NSTATE + n]);
    float hr = 0.f, hi = 0.f;
    for (int c = 0; c < NC; ++c) {
        const size_t cb = (size_t)(b * NC + c) * DDIM + d;
        const float mr = mid_hr[cb * NSTATE + n];
        const float mi = mid_hi[cb * NSTATE + n];
        mid_hr[cb * NSTATE + n] = hr;     // initial state for chunk c
        mid_hi[cb * NSTATE + n] = hi;
        const float P = __expf(A_dn * dtsum[cb]);
        hr = mr + P * hr;
        hi = mi + P * hi;
    }
}

// ---------------- phase 3: recompute with true init, emit y (+D_skip) ----------------
__global__ __launch_bounds__(256) void scan_phase3(
    const float* __restrict__ dt, const float* __restrict__ gr, const float* __restrict__ gi,
    const float* __restrict__ Bm, const float* __restrict__ Cm,
    const float* __restrict__ A_log, const float* __restrict__ D_skip,
    const float* __restrict__ hinit_r, const float* __restrict__ hinit_i,
    float* __restrict__ yr, float* __restrict__ yi)
{
    __shared__ float bm_s[LC * NSTATE], cm_s[LC * NSTATE];
    const int blk = blockIdx.x;
    const int dblk = blk & 1;
    const int c = (blk >> 1) & (NC - 1);
    const int b = blk >> 8;
    const int tid = threadIdx.x;
    const int d = dblk * 256 + tid;
    const int s0 = c * LC;
    {
        const size_t base = ((size_t)b * SSEQ + s0) * NSTATE;
        bm_s[tid] = Bm[base + tid];
        cm_s[tid] = Cm[base + tid];
    }
    float A_dn[16], hr[16], hi[16];
    const size_t mbase = ((size_t)(b * NC + c) * DDIM + d) * NSTATE;
    #pragma unroll
    for (int n = 0; n < 16; ++n) {
        A_dn[n] = -__expf(A_log[d * NSTATE + n]);
        hr[n] = hinit_r[mbase + n];
        hi[n] = hinit_i[mbase + n];
    }
    const float dsk = D_skip[d];
    __syncthreads();
    const size_t gbase = (size_t)b * SSEQ * DDIM + (size_t)s0 * DDIM + d;
    for (int i = 0; i < LC; ++i) {
        const float dtv = dt[gbase + (size_t)i * DDIM];
        const float ur = gr[gbase + (size_t)i * DDIM];
        const float ui = gi[gbase + (size_t)i * DDIM];
        const float xr = dtv * ur, xi = dtv * ui;
        float accr = dsk * ur, acci = dsk * ui;
        #pragma unroll
        for (int n = 0; n < 16; ++n) {
            const float a = __expf(dtv * A_dn[n]);
            const float bmv = bm_s[i * 16 + n], cmv = cm_s[i * 16 + n];
            hr[n] = a * hr[n] + xr * bmv;
            hi[n] = a * hi[n] + xi * bmv;
            accr += hr[n] * cmv;
            acci += hi[n] * cmv;
        }
        yr[gbase + (size_t)i * DDIM] = accr;
        yi[gbase + (size_t)i * DDIM] = acci;
    }
}

// ---------------- diag[b,d] = mean_s |branch|^2 (256 blocks) ----------------
__global__ __launch_bounds__(256) void diag_kernel(
    const float* __restrict__ br, const float* __restrict__ bi, float* __restrict__ diag)
{
    const int b = blockIdx.x >> 6;
    const int s0 = (blockIdx.x & 63) * 32;
    const int t = threadIdx.x;
    float a0 = 0.f, a1 = 0.f;
    for (int i = 0; i < 32; ++i) {
        const size_t g = (size_t)b * SSEQ * DDIM + (size_t)(s0 + i) * DDIM;
        const float r0 = br[g + t], i0 = bi[g + t];
        const float r1 = br[g + t + 256], i1 = bi[g + t + 256];
        a0 += r0 * r0 + i0 * i0;
        a1 += r1 * r1 + i1 * i1;
    }
    const float inv = 1.0f / (float)SSEQ;
    atomicAdd(&diag[b * DDIM + t], a0 * inv);
    atomicAdd(&diag[b * DDIM + t + 256], a1 * inv);
}

// ---------------- escape flags + sinkhorn coef + rotation table ----------------
__global__ __launch_bounds__(256) void escape_kernel(
    const float* __restrict__ diag, const float* __restrict__ phi,
    const float* __restrict__ logit, const float* __restrict__ logit_im,
    float* __restrict__ misc, float* __restrict__ rot_r, float* __restrict__ rot_i)
{
    const int tid = threadIdx.x;
    rot_r[tid] = cosf(phi[tid]);
    rot_i[tid] = sinf(phi[tid]);
    rot_r[tid + 256] = cosf(phi[tid + 256]);
    rot_i[tid + 256] = sinf(phi[tid + 256]);
    const int b = tid >> 6, lane = tid & 63;
    float mx = -1e30f, mn = 1e30f;
    for (int j = lane; j < DDIM; j += 64) {
        const float v = diag[b * DDIM + j];
        mx = fmaxf(mx, v);
        mn = fminf(mn, v);
    }
    #pragma unroll
    for (int off = 32; off; off >>= 1) {
        mx = fmaxf(mx, __shfl_xor(mx, off));
        mn = fminf(mn, __shfl_xor(mn, off));
    }
    if (lane == 0) {
        const float cond = mx / (mn + 1e-8f);
        misc[b] = (cond > CONDT_) ? 1.0f : 0.0f;
    }
    if (tid == 0) {
        float M = expf(logit[0] / 0.05f);
        for (int it = 0; it < 10; ++it) { M = M / M; M = M / M; }
        const float im = logit_im[0];
        misc[4] = M * cosf(im);
        misc[5] = M * sinf(im);
    }
}

// ---------------- final combine (float4) ----------------
__global__ __launch_bounds__(256) void final_kernel(
    const float* __restrict__ xr, const float* __restrict__ xi,
    const float* __restrict__ br, const float* __restrict__ bi,
    const float* __restrict__ misc, const float* __restrict__ rot_r,
    const float* __restrict__ rot_i, float* __restrict__ out)
{
    const size_t idx = ((size_t)blockIdx.x * 256 + threadIdx.x) * 4;  // < BSD
    const int d = (int)(idx % DDIM);
    const int b = (int)(idx / ((size_t)SSEQ * DDIM));
    float4 r = *reinterpret_cast<const float4*>(br + idx);
    float4 im = *reinterpret_cast<const float4*>(bi + idx);
    if (misc[b] != 0.0f) {
        const float4 rr = *reinterpret_cast<const float4*>(rot_r + d);
        const float4 ri = *reinterpret_cast<const float4*>(rot_i + d);
        float4 nr, ni;
        nr.x = r.x * rr.x - im.x * ri.x; ni.x = r.x * ri.x + im.x * rr.x;
        nr.y = r.y * rr.y - im.y * ri.y; ni.y = r.y * ri.y + im.y * rr.y;
        nr.z = r.z * rr.z - im.z * ri.z; ni.z = r.z * ri.z + im.z * rr.z;
        nr.w = r.w * rr.w - im.w * ri.w; ni.w = r.w * ri.w + im.w * rr.w;
        r = nr; im = ni;
    }
    const float cr = misc[4] * SCALE_, ci = misc[5] * SCALE_;
    const float4 x4 = *reinterpret_cast<const float4*>(xr + idx);
    const float4 y4 = *reinterpret_cast<const float4*>(xi + idx);
    float4 o0, o1;
    o0.x = x4.x + r.x * cr - im.x * ci; o1.x = y4.x + im.x * cr + r.x * ci;
    o0.y = x4.y + r.y * cr - im.y * ci; o1.y = y4.y + im.y * cr + r.y * ci;
    o0.z = x4.z + r.z * cr - im.z * ci; o1.z = y4.z + im.z * cr + r.z * ci;
    o0.w = x4.w + r.w * cr - im.w * ci; o1.w = y4.w + im.w * cr + r.w * ci;
    *reinterpret_cast<float4*>(out + idx) = o0;
    *reinterpret_cast<float4*>(out + BSD + idx) = o1;
}

extern "C" void kernel_launch(void* const* d_in, const int* in_sizes, int n_in,
                              void* d_out, int out_size, void* d_ws, size_t ws_size,
                              hipStream_t stream)
{
    (void)in_sizes; (void)n_in; (void)out_size; (void)ws_size;
    const float* x_r    = (const float*)d_in[0];
    const float* x_i    = (const float*)d_in[1];
    const float* Win_r  = (const float*)d_in[2];
    const float* Win_i  = (const float*)d_in[3];
    const float* convw  = (const float*)d_in[4];
    const float* W_dt   = (const float*)d_in[5];
    const float* b_dt   = (const float*)d_in[6];
    const float* A_log  = (const float*)d_in[7];
    const float* W_B    = (const float*)d_in[8];
    const float* W_C    = (const float*)d_in[9];
    const float* D_skip = (const float*)d_in[10];
    const float* Wout_r = (const float*)d_in[11];
    const float* Wout_i = (const float*)d_in[12];
    const float* L_r    = (const float*)d_in[13];
    const float* L_i    = (const float*)d_in[14];
    const float* phi    = (const float*)d_in[15];
    const float* hres   = (const float*)d_in[16];
    const float* hresi  = (const float*)d_in[17];
    float* out = (float*)d_out;

    float* f    = (float*)d_ws;
    float* u_r  = f;
    float* u_i  = f + BSD;
    float* g_r  = f + 2 * BSD;
    float* g_i  = f + 3 * BSD;
    float* dt   = f + 4 * BSD;
    float* y_r  = f + 5 * BSD;
    float* y_i  = f + 6 * BSD;
    float* Bm   = f + 7 * BSD;
    float* Cm   = Bm + BSN;
    float* dtsum = Cm + BSN;                       // BB*NC*DDIM = 262144
    float* diag = dtsum + (size_t)BB * NC * DDIM;
    float* misc = diag + (size_t)BB * DDIM;
    float* rot_r = misc + 8;
    float* rot_i = rot_r + DDIM;
    unsigned short* wbase = (unsigned short*)(rot_i + DDIM);
    unsigned short* WinT_r  = wbase;
    unsigned short* WinT_i  = wbase + 1 * 262144;
    unsigned short* WoutT_r = wbase + 2 * 262144;
    unsigned short* WoutT_i = wbase + 3 * 262144;
    unsigned short* WdtT    = wbase + 4 * 262144;   // [576][512]
    // scan scratch aliased into dead u buffers (u dead after conv_gate).
    float* mid_hr  = u_r;
    float* mid_hi  = u_i;
    float* br_r = u_r;   // branch output reuses u after phase3 consumed mid
    float* br_i = u_i;

    // 0. weight conversion (fp32 [K][N] -> bf16 [N][K]; + B/C strip into WdtT)
    convert_weights<<<64, 256, 0, stream>>>(Win_r, Win_i, Wout_r, Wout_i, W_dt,
                                            WinT_r, WinT_i, WoutT_r, WoutT_i, WdtT);
    convert_bc<<<128, 256, 0, stream>>>(W_B, W_C, WdtT);
    // 1. complex in-projection (MFMA, XCD-swizzled, double-buffered)
    cgemm_mfma<false><<<1024, 256, 0, stream>>>(
        x_r, x_i, WinT_r, WinT_i, nullptr, nullptr, u_r, u_i);
    // 2. causal conv + modSiLU gate (float4)
    conv_gate_kernel<<<(int)(BSD / 1024), 256, 0, stream>>>(u_r, u_i, convw, g_r, g_i);
    // 3. fused dt + B/C projections (MFMA, XCD-swizzled, double-buffered)
    rgemm_fused<<<1152, 256, 0, stream>>>(g_r, WdtT, b_dt, dt, Bm, Cm);
    // 4. chunked selective scan (+ D_skip)
    scan_phase1<<<BB * NC * 2, 256, 0, stream>>>(dt, g_r, g_i, Bm, A_log, mid_hr, mid_hi, dtsum);
    scan_phase2<<<128, 256, 0, stream>>>(mid_hr, mid_hi, dtsum, A_log);
    scan_phase3<<<BB * NC * 2, 256, 0, stream>>>(dt, g_r, g_i, Bm, Cm, A_log, D_skip,
                                                 mid_hr, mid_hi, y_r, y_i);
    // 5. complex out-projection (MFMA, + Lindblad scale)
    cgemm_mfma<true><<<1024, 256, 0, stream>>>(
        y_r, y_i, WoutT_r, WoutT_i, L_r, L_i, br_r, br_i);
    // 6. diag power + escape + coef
    hipMemsetAsync(diag, 0, (size_t)BB * DDIM * sizeof(float), stream);
    diag_kernel<<<256, 256, 0, stream>>>(br_r, br_i, diag);
    escape_kernel<<<1, 256, 0, stream>>>(diag, phi, hres, hresi, misc, rot_r, rot_i);
    // 7. final combine (float4)
    final_kernel<<<(int)(BSD / 1024), 256, 0, stream>>>(
        x_r, x_i, br_r, br_i, misc, rot_r, rot_i, out);
}